// Round 3
// baseline (166.281 us; speedup 1.0000x reference)
//
#include <hip/hip_runtime.h>
#include <hip/hip_bf16.h>
#include <stdint.h>

#define TT 2048
#define DD 1024
#define NH 16
#define DK 64

typedef __attribute__((ext_vector_type(8))) short bf16x8;
typedef __attribute__((ext_vector_type(4))) float f32x4;
typedef __attribute__((ext_vector_type(8))) unsigned short u16x8;
typedef __attribute__((ext_vector_type(4))) unsigned short u16x4;

__device__ __forceinline__ unsigned short f2bf(float f) {
  union { float f; unsigned u; } x; x.f = f;
  unsigned r = (x.u + 0x7FFFu + ((x.u >> 16) & 1u)) >> 16;
  return (unsigned short)r;
}

__device__ __forceinline__ void gload16(const void* g, void* l) {
  __builtin_amdgcn_global_load_lds(
      (const __attribute__((address_space(1))) unsigned int*)g,
      (__attribute__((address_space(3))) unsigned int*)l, 16, 0, 0);
}

// ---------------- convert f32 -> bf16 ----------------
__global__ __launch_bounds__(256) void cvt_all(
    const float* __restrict__ q, const float* __restrict__ k, const float* __restrict__ v,
    const float* __restrict__ wq, const float* __restrict__ wk, const float* __restrict__ wv,
    const float* __restrict__ wo,
    unsigned short* __restrict__ oq, unsigned short* __restrict__ ok, unsigned short* __restrict__ ov,
    unsigned short* __restrict__ owq, unsigned short* __restrict__ owk, unsigned short* __restrict__ owv,
    unsigned short* __restrict__ owo) {
  int b = blockIdx.x;
  const float* src; unsigned short* dst; int sb;
  if (b < 1024)      { src = q;  dst = oq;  sb = b; }
  else if (b < 2048) { src = k;  dst = ok;  sb = b - 1024; }
  else if (b < 3072) { src = v;  dst = ov;  sb = b - 2048; }
  else if (b < 3584) { src = wq; dst = owq; sb = b - 3072; }
  else if (b < 4096) { src = wk; dst = owk; sb = b - 3584; }
  else if (b < 4608) { src = wv; dst = owv; sb = b - 4096; }
  else               { src = wo; dst = owo; sb = b - 4608; }
  size_t i0 = (size_t)sb * 2048 + (size_t)threadIdx.x * 8;
  f32x4 a = *(const f32x4*)(src + i0);
  f32x4 c = *(const f32x4*)(src + i0 + 4);
  u16x8 r;
#pragma unroll
  for (int j = 0; j < 4; ++j) { r[j] = f2bf(a[j]); r[j + 4] = f2bf(c[j]); }
  *(u16x8*)(dst + i0) = r;
}

// ---------------- RoPE cos/sin table ----------------
__global__ __launch_bounds__(256) void rope_tab(const int* __restrict__ pos,
                                                float* __restrict__ cosT,
                                                float* __restrict__ sinT) {
  int idx = blockIdx.x * 256 + threadIdx.x;  // 2048*32
  int t = idx >> 5, i = idx & 31;
  float inv = exp2f((float)i * -0.41524101186092028f);  // 10000^(-i/32)
  float ang = (float)pos[t] * inv;
  cosT[idx] = cosf(ang);
  sinT[idx] = sinf(ang);
}

// ---------------- fused QKV projection + RoPE ----------------
__global__ __launch_bounds__(256) void gemm_qkv(
    const unsigned short* __restrict__ xq, const unsigned short* __restrict__ xk,
    const unsigned short* __restrict__ xv,
    const unsigned short* __restrict__ wqb, const unsigned short* __restrict__ wkb,
    const unsigned short* __restrict__ wvb,
    unsigned short* __restrict__ Qh, unsigned short* __restrict__ Kh,
    unsigned short* __restrict__ Vt,
    const float* __restrict__ cosT, const float* __restrict__ sinT) {
  __shared__ unsigned short Ash[128 * 64];
  __shared__ unsigned short Bsh[128 * 64];
  const int z = blockIdx.z;
  const unsigned short* A = (z == 0) ? xq : (z == 1) ? xk : xv;
  const unsigned short* W = (z == 0) ? wqb : (z == 1) ? wkb : wvb;
  const int brow = blockIdx.x * 128;
  const int bcol = blockIdx.y * 128;
  const int tid = threadIdx.x;
  const int lane = tid & 63;
  const int w = tid >> 6;
  const int wr = w >> 1, wc = w & 1;
  const char* Ab = (const char*)A + (size_t)brow * (DD * 2);
  const char* Wb = (const char*)W + (size_t)bcol * (DD * 2);
  char* AshB = (char*)Ash;
  char* BshB = (char*)Bsh;
  f32x4 acc[4][4];
#pragma unroll
  for (int mi = 0; mi < 4; ++mi)
#pragma unroll
    for (int ni = 0; ni < 4; ++ni)
#pragma unroll
      for (int r = 0; r < 4; ++r) acc[mi][ni][r] = 0.0f;

  for (int k0 = 0; k0 < DD; k0 += 64) {
    __syncthreads();
#pragma unroll
    for (int it = 0; it < 4; ++it) {
      int c = it * 256 + tid;
      int row = c >> 3;
      int xb = (c & 7) << 4;
      int sxb = xb ^ ((row & 7) << 4);
      int ldso = (it * 256 + (tid & 192)) << 4;
      gload16(Ab + (size_t)row * (DD * 2) + k0 * 2 + sxb, AshB + ldso);
      gload16(Wb + (size_t)row * (DD * 2) + k0 * 2 + sxb, BshB + ldso);
    }
    __syncthreads();
#pragma unroll
    for (int ks = 0; ks < 2; ++ks) {
      bf16x8 af[4], bfr[4];
      int colb = ks * 64 + ((lane >> 4) << 4);
#pragma unroll
      for (int mi = 0; mi < 4; ++mi) {
        int row = wr * 64 + mi * 16 + (lane & 15);
        af[mi] = *(const bf16x8*)(AshB + row * 128 + (colb ^ ((row & 7) << 4)));
      }
#pragma unroll
      for (int ni = 0; ni < 4; ++ni) {
        int row = wc * 64 + ni * 16 + (lane & 15);
        bfr[ni] = *(const bf16x8*)(BshB + row * 128 + (colb ^ ((row & 7) << 4)));
      }
#pragma unroll
      for (int mi = 0; mi < 4; ++mi)
#pragma unroll
        for (int ni = 0; ni < 4; ++ni)
          acc[mi][ni] = __builtin_amdgcn_mfma_f32_16x16x32_bf16(af[mi], bfr[ni], acc[mi][ni], 0, 0, 0);
    }
  }

  const int hcol = bcol + wc * 64;
  const int h = hcol >> 6;
  if (z < 2) {
    unsigned short* OUT = (z == 0) ? Qh : Kh;
    // Q scale: 1/sqrt(64) * log2(e)  (scores land in log2 domain -> exp2 softmax)
    const float sc = (z == 0) ? 0.18033688011112042f : 1.0f;
#pragma unroll
    for (int mi = 0; mi < 4; ++mi) {
#pragma unroll
      for (int r = 0; r < 4; ++r) {
        int t = brow + wr * 64 + mi * 16 + ((lane >> 4) << 2) + r;
#pragma unroll
        for (int ni = 0; ni < 2; ++ni) {
          int dl = ni * 16 + (lane & 15);
          float cv = cosT[t * 32 + dl];
          float sv = sinT[t * 32 + dl];
          float x1 = acc[mi][ni][r];
          float x2 = acc[mi][ni + 2][r];
          size_t base = ((size_t)h * TT + t) * DK + dl;
          OUT[base] = f2bf((x1 * cv - x2 * sv) * sc);
          OUT[base + 32] = f2bf((x2 * cv + x1 * sv) * sc);
        }
      }
    }
  } else {
#pragma unroll
    for (int mi = 0; mi < 4; ++mi) {
#pragma unroll
      for (int ni = 0; ni < 4; ++ni) {
        int dh = ni * 16 + (lane & 15);
        int t0 = brow + wr * 64 + mi * 16 + ((lane >> 4) << 2);
        u16x4 pk;
#pragma unroll
        for (int r = 0; r < 4; ++r) pk[r] = f2bf(acc[mi][ni][r]);
        *(u16x4*)((char*)Vt + (((size_t)h * DK + dh) * TT + t0) * 2) = pk;
      }
    }
  }
}

// ---------------- split-K causal flash attention ----------------
__device__ __forceinline__ void load_kfrag(const char* Kb, int k0, int lane,
                                           bf16x8 kf[2][4]) {
#pragma unroll
  for (int ks = 0; ks < 2; ++ks)
#pragma unroll
    for (int ni = 0; ni < 4; ++ni) {
      const char* p = Kb + (size_t)(k0 + ni * 16 + (lane & 15)) * 128 + ks * 64 +
                      ((lane >> 4) << 4);
      kf[ks][ni] = *(const bf16x8*)p;
    }
}

__device__ __forceinline__ void load_vfrag(const char* Vb, int k0, int lane,
                                           bf16x8 vf[2][4]) {
#pragma unroll
  for (int ks = 0; ks < 2; ++ks)
#pragma unroll
    for (int ni = 0; ni < 4; ++ni) {
      const char* p = Vb + (size_t)(ni * 16 + (lane & 15)) * (TT * 2) +
                      (k0 + ks * 32) * 2 + ((lane >> 4) << 4);
      vf[ks][ni] = *(const bf16x8*)p;
    }
}

// 1 wave per block. split=1: 2560 jobs (head, qw, kv-chunk<=8 tiles); else 1024.
// bid&7 pins job's head-pair to one XCD (L2 locality: 2 heads ~1.5MB < 4MB).
__global__ __launch_bounds__(64) void attn_fa(
    const unsigned short* __restrict__ Qh, const unsigned short* __restrict__ Kh,
    const unsigned short* __restrict__ Vt, unsigned short* __restrict__ AO,
    float* __restrict__ PO, float* __restrict__ PML, int split) {
  __shared__ unsigned short Psh[32 * 64];
  const int lane = threadIdx.x;
  const int bid = blockIdx.x;
  const int xcd = bid & 7;
  const int idx = bid >> 3;
  int h, qw, c, nc;
  if (split) {
    h = (idx / 160) * 8 + xcd;
    int jj = idx % 160;
    if (jj < 16)      { qw = jj;                    c = 0;             nc = 1; }
    else if (jj < 48) { qw = 16 + ((jj - 16) >> 1); c = (jj - 16) & 1; nc = 2; }
    else if (jj < 96) { qw = 32 + (jj - 48) / 3;    c = (jj - 48) % 3; nc = 3; }
    else              { qw = 48 + ((jj - 96) >> 2); c = (jj - 96) & 3; nc = 4; }
  } else {
    h = (idx / 64) * 8 + xcd;
    qw = idx & 63; c = 0; nc = 1;
  }
  const int q0w = qw * 32;
  const int NT = (qw >> 1) + 1;
  const int tA = c * 8;
  const int tB = min(tA + 8, NT);
  char* PshB = (char*)Psh;
  const char* Kb = (const char*)Kh + (size_t)h * TT * DK * 2;
  const char* Vb = (const char*)Vt + (size_t)h * DK * TT * 2;

  bf16x8 qf[2][2];
#pragma unroll
  for (int mi = 0; mi < 2; ++mi)
#pragma unroll
    for (int ks = 0; ks < 2; ++ks) {
      const unsigned short* p =
          Qh + ((size_t)h * TT + q0w + mi * 16 + (lane & 15)) * DK + ks * 32 + ((lane >> 4) << 3);
      qf[mi][ks] = *(const bf16x8*)p;
    }

  bf16x8 vone;
#pragma unroll
  for (int j = 0; j < 8; ++j) vone[j] = (short)0x3F80;  // bf16 1.0

  f32x4 accO[2][5];  // [..][4] = row-sum l via ones-column MFMA
  float mrow[2][4];
#pragma unroll
  for (int mi = 0; mi < 2; ++mi) {
#pragma unroll
    for (int ni = 0; ni < 5; ++ni)
#pragma unroll
      for (int r = 0; r < 4; ++r) accO[mi][ni][r] = 0.0f;
#pragma unroll
    for (int r = 0; r < 4; ++r) mrow[mi][r] = -1e30f;
  }

  bf16x8 kfA[2][4], kfB[2][4], vf[2][4];
  load_kfrag(Kb, tA * 64, lane, kfA);
#pragma unroll
  for (int ks = 0; ks < 2; ++ks)
#pragma unroll
    for (int ni = 0; ni < 4; ++ni) kfB[ks][ni] = kfA[ks][ni];

  for (int kt = tA; kt < tB; ++kt) {
    const int k0 = kt * 64;
    load_vfrag(Vb, k0, lane, vf);
    f32x4 s[2][4];
#pragma unroll
    for (int mi = 0; mi < 2; ++mi)
#pragma unroll
      for (int ni = 0; ni < 4; ++ni)
#pragma unroll
        for (int r = 0; r < 4; ++r) s[mi][ni][r] = 0.0f;
#pragma unroll
    for (int ks = 0; ks < 2; ++ks)
#pragma unroll
      for (int mi = 0; mi < 2; ++mi)
#pragma unroll
        for (int ni = 0; ni < 4; ++ni)
          s[mi][ni] = __builtin_amdgcn_mfma_f32_16x16x32_bf16(qf[mi][ks], kfA[ks][ni], s[mi][ni], 0, 0, 0);
    if (kt + 1 < tB) load_kfrag(Kb, k0 + 64, lane, kfB);

    if (kt == NT - 1) {  // diagonal tile: causal mask (scores in log2 domain)
#pragma unroll
      for (int mi = 0; mi < 2; ++mi)
#pragma unroll
        for (int ni = 0; ni < 4; ++ni)
#pragma unroll
          for (int r = 0; r < 4; ++r) {
            int qq = q0w + mi * 16 + ((lane >> 4) << 2) + r;
            int kk = k0 + ni * 16 + (lane & 15);
            if (kk > qq) s[mi][ni][r] = -1e30f;
          }
    }
#pragma unroll
    for (int mi = 0; mi < 2; ++mi) {
      f32x4 rmx = s[mi][0];
#pragma unroll
      for (int ni = 1; ni < 4; ++ni)
#pragma unroll
        for (int r = 0; r < 4; ++r) rmx[r] = fmaxf(rmx[r], s[mi][ni][r]);
#pragma unroll
      for (int d = 1; d < 16; d <<= 1)
#pragma unroll
        for (int r = 0; r < 4; ++r) rmx[r] = fmaxf(rmx[r], __shfl_xor(rmx[r], d, 64));
      float alpha[4];
#pragma unroll
      for (int r = 0; r < 4; ++r) {
        float mo = mrow[mi][r];
        float mn = fmaxf(mo, rmx[r]);
        alpha[r] = exp2f(mo - mn);
        mrow[mi][r] = mn;
      }
#pragma unroll
      for (int ni = 0; ni < 5; ++ni)
#pragma unroll
        for (int r = 0; r < 4; ++r) accO[mi][ni][r] *= alpha[r];
#pragma unroll
      for (int ni = 0; ni < 4; ++ni)
#pragma unroll
        for (int r = 0; r < 4; ++r) {
          float p = exp2f(s[mi][ni][r] - mrow[mi][r]);
          int row = mi * 16 + ((lane >> 4) << 2) + r;
          int cb = (ni * 16 + (lane & 15)) * 2;
          *(short*)(PshB + row * 128 + (cb ^ ((row & 7) << 4))) = (short)f2bf(p);
        }
    }
    asm volatile("" ::: "memory");  // order P writes before P reads (wave-local)
#pragma unroll
    for (int ks = 0; ks < 2; ++ks) {
      int colb = ks * 64 + ((lane >> 4) << 4);
      bf16x8 pf[2];
#pragma unroll
      for (int mi = 0; mi < 2; ++mi) {
        int row = mi * 16 + (lane & 15);
        pf[mi] = *(const bf16x8*)(PshB + row * 128 + (colb ^ ((row & 7) << 4)));
      }
#pragma unroll
      for (int mi = 0; mi < 2; ++mi) {
#pragma unroll
        for (int ni = 0; ni < 4; ++ni)
          accO[mi][ni] = __builtin_amdgcn_mfma_f32_16x16x32_bf16(pf[mi], vf[ks][ni], accO[mi][ni], 0, 0, 0);
        accO[mi][4] = __builtin_amdgcn_mfma_f32_16x16x32_bf16(pf[mi], vone, accO[mi][4], 0, 0, 0);
      }
    }
#pragma unroll
    for (int ks = 0; ks < 2; ++ks)
#pragma unroll
      for (int ni = 0; ni < 4; ++ni) kfA[ks][ni] = kfB[ks][ni];
  }

  if (nc == 1) {
#pragma unroll
    for (int mi = 0; mi < 2; ++mi)
#pragma unroll
      for (int ni = 0; ni < 4; ++ni)
#pragma unroll
        for (int r = 0; r < 4; ++r) {
          int t = q0w + mi * 16 + ((lane >> 4) << 2) + r;
          int dh = ni * 16 + (lane & 15);
          AO[(size_t)t * DD + h * DK + dh] = f2bf(accO[mi][ni][r] / accO[mi][4][r]);
        }
  } else {
    const int slot = (h * 64 + qw) * 4 + c;
    float* po = PO + (size_t)slot * 2048;
#pragma unroll
    for (int mi = 0; mi < 2; ++mi)
#pragma unroll
      for (int ni = 0; ni < 4; ++ni)
#pragma unroll
        for (int r = 0; r < 4; ++r) {
          int row = mi * 16 + ((lane >> 4) << 2) + r;
          po[row * 64 + ni * 16 + (lane & 15)] = accO[mi][ni][r];
        }
    if ((lane & 15) == 0) {
      float* pml = PML + slot * 64;
#pragma unroll
      for (int mi = 0; mi < 2; ++mi)
#pragma unroll
        for (int r = 0; r < 4; ++r) {
          int row = mi * 16 + ((lane >> 4) << 2) + r;
          pml[row] = mrow[mi][r];
          pml[32 + row] = accO[mi][4][r];
        }
    }
  }
}

// merge chunk partials for qw >= 16; grid (48, 16), 64 threads (lane = d)
__global__ __launch_bounds__(64) void attn_combine(
    const float* __restrict__ PO, const float* __restrict__ PML,
    unsigned short* __restrict__ AO) {
  const int qw = 16 + (int)blockIdx.x;
  const int h = blockIdx.y;
  const int lane = threadIdx.x;
  const int nc = (((qw >> 1) + 1) + 7) >> 3;
  const int slot0 = (h * 64 + qw) * 4;
  const int q0w = qw * 32;
  for (int row = 0; row < 32; ++row) {
    float M = -1e30f;
    for (int cc = 0; cc < nc; ++cc) M = fmaxf(M, PML[(slot0 + cc) * 64 + row]);
    float acc = 0.0f, lsum = 0.0f;
    for (int cc = 0; cc < nc; ++cc) {
      float wgt = exp2f(PML[(slot0 + cc) * 64 + row] - M);
      acc += wgt * PO[(size_t)(slot0 + cc) * 2048 + row * 64 + lane];
      lsum += wgt * PML[(slot0 + cc) * 64 + 32 + row];
    }
    AO[(size_t)(q0w + row) * DD + h * DK + lane] = f2bf(acc / lsum);
  }
}

// ---------------- output projection + bias (f32 out) ----------------
__global__ __launch_bounds__(256) void gemm_o(
    const unsigned short* __restrict__ A, const unsigned short* __restrict__ W,
    const float* __restrict__ bias, float* __restrict__ out) {
  __shared__ unsigned short Ash[128 * 64];
  __shared__ unsigned short Bsh[128 * 64];
  const int brow = blockIdx.x * 128;
  const int bcol = blockIdx.y * 128;
  const int tid = threadIdx.x;
  const int lane = tid & 63;
  const int w = tid >> 6;
  const int wr = w >> 1, wc = w & 1;
  const char* Ab = (const char*)A + (size_t)brow * (DD * 2);
  const char* Wb = (const char*)W + (size_t)bcol * (DD * 2);
  char* AshB = (char*)Ash;
  char* BshB = (char*)Bsh;
  f32x4 acc[4][4];
#pragma unroll
  for (int mi = 0; mi < 4; ++mi)
#pragma unroll
    for (int ni = 0; ni < 4; ++ni)
#pragma unroll
      for (int r = 0; r < 4; ++r) acc[mi][ni][r] = 0.0f;

  for (int k0 = 0; k0 < DD; k0 += 64) {
    __syncthreads();
#pragma unroll
    for (int it = 0; it < 4; ++it) {
      int c = it * 256 + tid;
      int row = c >> 3;
      int xb = (c & 7) << 4;
      int sxb = xb ^ ((row & 7) << 4);
      int ldso = (it * 256 + (tid & 192)) << 4;
      gload16(Ab + (size_t)row * (DD * 2) + k0 * 2 + sxb, AshB + ldso);
      gload16(Wb + (size_t)row * (DD * 2) + k0 * 2 + sxb, BshB + ldso);
    }
    __syncthreads();
#pragma unroll
    for (int ks = 0; ks < 2; ++ks) {
      bf16x8 af[4], bfr[4];
      int colb = ks * 64 + ((lane >> 4) << 4);
#pragma unroll
      for (int mi = 0; mi < 4; ++mi) {
        int row = wr * 64 + mi * 16 + (lane & 15);
        af[mi] = *(const bf16x8*)(AshB + row * 128 + (colb ^ ((row & 7) << 4)));
      }
#pragma unroll
      for (int ni = 0; ni < 4; ++ni) {
        int row = wc * 64 + ni * 16 + (lane & 15);
        bfr[ni] = *(const bf16x8*)(BshB + row * 128 + (colb ^ ((row & 7) << 4)));
      }
#pragma unroll
      for (int mi = 0; mi < 4; ++mi)
#pragma unroll
        for (int ni = 0; ni < 4; ++ni)
          acc[mi][ni] = __builtin_amdgcn_mfma_f32_16x16x32_bf16(af[mi], bfr[ni], acc[mi][ni], 0, 0, 0);
    }
  }
#pragma unroll
  for (int mi = 0; mi < 4; ++mi)
#pragma unroll
    for (int r = 0; r < 4; ++r) {
      int t = brow + wr * 64 + mi * 16 + ((lane >> 4) << 2) + r;
#pragma unroll
      for (int ni = 0; ni < 4; ++ni) {
        int o = bcol + wc * 64 + ni * 16 + (lane & 15);
        out[(size_t)t * DD + o] = acc[mi][ni][r] + bias[o];
      }
    }
}

// ---------------- launch ----------------
extern "C" void kernel_launch(void* const* d_in, const int* in_sizes, int n_in,
                              void* d_out, int out_size, void* d_ws, size_t ws_size,
                              hipStream_t stream) {
  const float* q  = (const float*)d_in[0];
  const float* k  = (const float*)d_in[1];
  const float* v  = (const float*)d_in[2];
  const int* pos  = (const int*)d_in[3];
  const float* wq = (const float*)d_in[4];
  const float* wk = (const float*)d_in[5];
  const float* wv = (const float*)d_in[6];
  const float* wo = (const float*)d_in[7];
  const float* wob = (const float*)d_in[8];
  float* out = (float*)d_out;
  char* ws = (char*)d_ws;

  const size_t MB = 1u << 20;
  unsigned short* XQ = (unsigned short*)(ws + 0 * MB);
  unsigned short* XK = (unsigned short*)(ws + 4 * MB);
  unsigned short* XV = (unsigned short*)(ws + 8 * MB);
  unsigned short* WQ = (unsigned short*)(ws + 12 * MB);
  unsigned short* WK = (unsigned short*)(ws + 14 * MB);
  unsigned short* WV = (unsigned short*)(ws + 16 * MB);
  unsigned short* WO = (unsigned short*)(ws + 18 * MB);
  unsigned short* QH = (unsigned short*)(ws + 20 * MB);
  unsigned short* KH = (unsigned short*)(ws + 24 * MB);
  unsigned short* VT = (unsigned short*)(ws + 28 * MB);
  unsigned short* AOb = (unsigned short*)(ws + 32 * MB);
  float* COS = (float*)(ws + 36 * MB);
  float* SIN = (float*)(ws + 36 * MB + 262144);
  float* PO  = (float*)(ws + 40 * MB);   // 16*64*4 slots * 8KB = 32MB
  float* PML = (float*)(ws + 72 * MB);   // 16*64*4 slots * 256B = 1MB

  const int split = (ws_size >= 74 * MB) ? 1 : 0;

  hipLaunchKernelGGL(cvt_all, dim3(5120), dim3(256), 0, stream,
                     q, k, v, wq, wk, wv, wo, XQ, XK, XV, WQ, WK, WV, WO);
  hipLaunchKernelGGL(rope_tab, dim3(256), dim3(256), 0, stream, pos, COS, SIN);
  hipLaunchKernelGGL(gemm_qkv, dim3(16, 8, 3), dim3(256), 0, stream,
                     XQ, XK, XV, WQ, WK, WV, QH, KH, VT, COS, SIN);
  hipLaunchKernelGGL(attn_fa, dim3(split ? 2560 : 1024), dim3(64), 0, stream,
                     QH, KH, VT, AOb, PO, PML, split);
  if (split)
    hipLaunchKernelGGL(attn_combine, dim3(48, 16), dim3(64), 0, stream, PO, PML, AOb);
  hipLaunchKernelGGL(gemm_o, dim3(16, 8), dim3(256), 0, stream, AOb, WO, wob, out);
}

// Round 4
// 110.576 us; speedup vs baseline: 1.5038x; 1.5038x over previous
//
#include <hip/hip_runtime.h>
#include <hip/hip_bf16.h>
#include <stdint.h>

#define TT 2048
#define DD 1024
#define NH 16
#define DK 64

typedef __attribute__((ext_vector_type(8))) short bf16x8;
typedef __attribute__((ext_vector_type(4))) float f32x4;
typedef __attribute__((ext_vector_type(8))) unsigned short u16x8;
typedef __attribute__((ext_vector_type(4))) unsigned short u16x4;

__device__ __forceinline__ unsigned short f2bf(float f) {
  union { float f; unsigned u; } x; x.f = f;
  unsigned r = (x.u + 0x7FFFu + ((x.u >> 16) & 1u)) >> 16;
  return (unsigned short)r;
}

__device__ __forceinline__ void gload16(const void* g, void* l) {
  __builtin_amdgcn_global_load_lds(
      (const __attribute__((address_space(1))) unsigned int*)g,
      (__attribute__((address_space(3))) unsigned int*)l, 16, 0, 0);
}

// ---------------- convert f32 -> bf16 ----------------
__global__ __launch_bounds__(256) void cvt_all(
    const float* __restrict__ q, const float* __restrict__ k, const float* __restrict__ v,
    const float* __restrict__ wq, const float* __restrict__ wk, const float* __restrict__ wv,
    const float* __restrict__ wo,
    unsigned short* __restrict__ oq, unsigned short* __restrict__ ok, unsigned short* __restrict__ ov,
    unsigned short* __restrict__ owq, unsigned short* __restrict__ owk, unsigned short* __restrict__ owv,
    unsigned short* __restrict__ owo) {
  int b = blockIdx.x;
  const float* src; unsigned short* dst; int sb;
  if (b < 1024)      { src = q;  dst = oq;  sb = b; }
  else if (b < 2048) { src = k;  dst = ok;  sb = b - 1024; }
  else if (b < 3072) { src = v;  dst = ov;  sb = b - 2048; }
  else if (b < 3584) { src = wq; dst = owq; sb = b - 3072; }
  else if (b < 4096) { src = wk; dst = owk; sb = b - 3584; }
  else if (b < 4608) { src = wv; dst = owv; sb = b - 4096; }
  else               { src = wo; dst = owo; sb = b - 4608; }
  size_t i0 = (size_t)sb * 2048 + (size_t)threadIdx.x * 8;
  f32x4 a = *(const f32x4*)(src + i0);
  f32x4 c = *(const f32x4*)(src + i0 + 4);
  u16x8 r;
#pragma unroll
  for (int j = 0; j < 4; ++j) { r[j] = f2bf(a[j]); r[j + 4] = f2bf(c[j]); }
  *(u16x8*)(dst + i0) = r;
}

// ---------------- RoPE cos/sin table ----------------
__global__ __launch_bounds__(256) void rope_tab(const int* __restrict__ pos,
                                                float* __restrict__ cosT,
                                                float* __restrict__ sinT) {
  int idx = blockIdx.x * 256 + threadIdx.x;  // 2048*32
  int t = idx >> 5, i = idx & 31;
  float inv = exp2f((float)i * -0.41524101186092028f);  // 10000^(-i/32)
  float ang = (float)pos[t] * inv;
  cosT[idx] = cosf(ang);
  sinT[idx] = sinf(ang);
}

// ---------------- fused QKV projection + RoPE ----------------
__global__ __launch_bounds__(256) void gemm_qkv(
    const unsigned short* __restrict__ xq, const unsigned short* __restrict__ xk,
    const unsigned short* __restrict__ xv,
    const unsigned short* __restrict__ wqb, const unsigned short* __restrict__ wkb,
    const unsigned short* __restrict__ wvb,
    unsigned short* __restrict__ Qh, unsigned short* __restrict__ Kh,
    unsigned short* __restrict__ Vt,
    const float* __restrict__ cosT, const float* __restrict__ sinT) {
  __shared__ unsigned short Ash[128 * 64];
  __shared__ unsigned short Bsh[128 * 64];
  const int z = blockIdx.z;
  const unsigned short* A = (z == 0) ? xq : (z == 1) ? xk : xv;
  const unsigned short* W = (z == 0) ? wqb : (z == 1) ? wkb : wvb;
  const int brow = blockIdx.x * 128;
  const int bcol = blockIdx.y * 128;
  const int tid = threadIdx.x;
  const int lane = tid & 63;
  const int w = tid >> 6;
  const int wr = w >> 1, wc = w & 1;
  const char* Ab = (const char*)A + (size_t)brow * (DD * 2);
  const char* Wb = (const char*)W + (size_t)bcol * (DD * 2);
  char* AshB = (char*)Ash;
  char* BshB = (char*)Bsh;
  f32x4 acc[4][4];
#pragma unroll
  for (int mi = 0; mi < 4; ++mi)
#pragma unroll
    for (int ni = 0; ni < 4; ++ni)
#pragma unroll
      for (int r = 0; r < 4; ++r) acc[mi][ni][r] = 0.0f;

  for (int k0 = 0; k0 < DD; k0 += 64) {
    __syncthreads();
#pragma unroll
    for (int it = 0; it < 4; ++it) {
      int c = it * 256 + tid;
      int row = c >> 3;
      int xb = (c & 7) << 4;
      int sxb = xb ^ ((row & 7) << 4);
      int ldso = (it * 256 + (tid & 192)) << 4;
      gload16(Ab + (size_t)row * (DD * 2) + k0 * 2 + sxb, AshB + ldso);
      gload16(Wb + (size_t)row * (DD * 2) + k0 * 2 + sxb, BshB + ldso);
    }
    __syncthreads();
#pragma unroll
    for (int ks = 0; ks < 2; ++ks) {
      bf16x8 af[4], bfr[4];
      int colb = ks * 64 + ((lane >> 4) << 4);
#pragma unroll
      for (int mi = 0; mi < 4; ++mi) {
        int row = wr * 64 + mi * 16 + (lane & 15);
        af[mi] = *(const bf16x8*)(AshB + row * 128 + (colb ^ ((row & 7) << 4)));
      }
#pragma unroll
      for (int ni = 0; ni < 4; ++ni) {
        int row = wc * 64 + ni * 16 + (lane & 15);
        bfr[ni] = *(const bf16x8*)(BshB + row * 128 + (colb ^ ((row & 7) << 4)));
      }
#pragma unroll
      for (int mi = 0; mi < 4; ++mi)
#pragma unroll
        for (int ni = 0; ni < 4; ++ni)
          acc[mi][ni] = __builtin_amdgcn_mfma_f32_16x16x32_bf16(af[mi], bfr[ni], acc[mi][ni], 0, 0, 0);
    }
  }

  const int hcol = bcol + wc * 64;
  const int h = hcol >> 6;
  if (z < 2) {
    unsigned short* OUT = (z == 0) ? Qh : Kh;
    // Q scale: 1/sqrt(64) * log2(e)  (scores land in log2 domain -> exp2 softmax)
    const float sc = (z == 0) ? 0.18033688011112042f : 1.0f;
#pragma unroll
    for (int mi = 0; mi < 4; ++mi) {
#pragma unroll
      for (int r = 0; r < 4; ++r) {
        int t = brow + wr * 64 + mi * 16 + ((lane >> 4) << 2) + r;
#pragma unroll
        for (int ni = 0; ni < 2; ++ni) {
          int dl = ni * 16 + (lane & 15);
          float cv = cosT[t * 32 + dl];
          float sv = sinT[t * 32 + dl];
          float x1 = acc[mi][ni][r];
          float x2 = acc[mi][ni + 2][r];
          size_t base = ((size_t)h * TT + t) * DK + dl;
          OUT[base] = f2bf((x1 * cv - x2 * sv) * sc);
          OUT[base + 32] = f2bf((x2 * cv + x1 * sv) * sc);
        }
      }
    }
  } else {
#pragma unroll
    for (int mi = 0; mi < 4; ++mi) {
#pragma unroll
      for (int ni = 0; ni < 4; ++ni) {
        int dh = ni * 16 + (lane & 15);
        int t0 = brow + wr * 64 + mi * 16 + ((lane >> 4) << 2);
        u16x4 pk;
#pragma unroll
        for (int r = 0; r < 4; ++r) pk[r] = f2bf(acc[mi][ni][r]);
        *(u16x4*)((char*)Vt + (((size_t)h * DK + dh) * TT + t0) * 2) = pk;
      }
    }
  }
}

// ---------------- causal flash attention ----------------
// grid 1024: job (h, qw=32-row q-block); 2 waves split odd/even k-tiles,
// merge at end via LDS (one barrier). Swapped QK^T (S^T layout), defer-max,
// l via ones-column MFMA. bid&7 pins head-pair to one XCD for L2 locality.
__device__ __forceinline__ void load_kfrag(const char* Kb, int k0, int lane,
                                           bf16x8 kf[2][4]) {
#pragma unroll
  for (int ks = 0; ks < 2; ++ks)
#pragma unroll
    for (int ni = 0; ni < 4; ++ni) {
      const char* p = Kb + (size_t)(k0 + ni * 16 + (lane & 15)) * 128 + ks * 64 +
                      ((lane >> 4) << 4);
      kf[ks][ni] = *(const bf16x8*)p;
    }
}

__device__ __forceinline__ void load_vfrag(const char* Vb, int k0, int lane,
                                           bf16x8 vf[2][4]) {
#pragma unroll
  for (int ks = 0; ks < 2; ++ks)
#pragma unroll
    for (int ni = 0; ni < 4; ++ni) {
      const char* p = Vb + (size_t)(ni * 16 + (lane & 15)) * (TT * 2) +
                      (k0 + ks * 32) * 2 + ((lane >> 4) << 4);
      vf[ks][ni] = *(const bf16x8*)p;
    }
}

__global__ __launch_bounds__(128) void attn_fa(
    const unsigned short* __restrict__ Qh, const unsigned short* __restrict__ Kh,
    const unsigned short* __restrict__ Vt, unsigned short* __restrict__ AO) {
  __shared__ unsigned short Psh[2][32 * 64];
  __shared__ float MO[32][68];   // wave1 partial O (cols 0..63) + l (col 64)
  __shared__ float MR[2][32];    // per-wave running max by q-row
  const int tid = threadIdx.x;
  const int lane = tid & 63;
  const int w = tid >> 6;
  const int bid = blockIdx.x;
  const int xcd = bid & 7;
  const int idx = bid >> 3;
  const int h = (idx >> 6) * 8 + xcd;
  const int qw = idx & 63;
  const int q0w = qw * 32;
  const int NT = (qw >> 1) + 1;
  char* PshB = (char*)&Psh[w][0];
  const char* Kb = (const char*)Kh + (size_t)h * TT * DK * 2;
  const char* Vb = (const char*)Vt + (size_t)h * DK * TT * 2;

  // Q fragments (B-operand for swapped QK^T: same per-lane layout as A)
  bf16x8 qf[2][2];
#pragma unroll
  for (int mi = 0; mi < 2; ++mi)
#pragma unroll
    for (int ks = 0; ks < 2; ++ks) {
      const unsigned short* p =
          Qh + ((size_t)h * TT + q0w + mi * 16 + (lane & 15)) * DK + ks * 32 + ((lane >> 4) << 3);
      qf[mi][ks] = *(const bf16x8*)p;
    }

  bf16x8 vone;
#pragma unroll
  for (int j = 0; j < 8; ++j) vone[j] = (short)0x3F80;  // bf16 1.0

  f32x4 accO[2][5];  // [..][4] = row-sum l (ones-column MFMA)
  float mrow[2];
#pragma unroll
  for (int mi = 0; mi < 2; ++mi) {
    mrow[mi] = -1e30f;
#pragma unroll
    for (int ni = 0; ni < 5; ++ni)
#pragma unroll
      for (int r = 0; r < 4; ++r) accO[mi][ni][r] = 0.0f;
  }

  bf16x8 kfA[2][4], kfB[2][4], vf[2][4];
  {
    int kt0 = (w < NT) ? w : 0;
    load_kfrag(Kb, kt0 * 64, lane, kfA);
  }

  for (int kt = w; kt < NT; kt += 2) {
    const int k0 = kt * 64;
    load_vfrag(Vb, k0, lane, vf);  // issue early; QK+softmax hides latency
    f32x4 s[2][4];
#pragma unroll
    for (int mi = 0; mi < 2; ++mi)
#pragma unroll
      for (int ni = 0; ni < 4; ++ni)
#pragma unroll
        for (int r = 0; r < 4; ++r) s[mi][ni][r] = 0.0f;
    // swapped: S^T[k][q] = K-frag (A) x Q-frag (B); row=k, col=q
#pragma unroll
    for (int ks = 0; ks < 2; ++ks)
#pragma unroll
      for (int mi = 0; mi < 2; ++mi)
#pragma unroll
        for (int ni = 0; ni < 4; ++ni)
          s[mi][ni] = __builtin_amdgcn_mfma_f32_16x16x32_bf16(kfA[ks][ni], qf[mi][ks], s[mi][ni], 0, 0, 0);
    if (kt + 2 < NT) load_kfrag(Kb, k0 + 128, lane, kfB);  // prefetch

    if (kt == NT - 1) {  // diagonal tile: causal mask
#pragma unroll
      for (int mi = 0; mi < 2; ++mi) {
        int qq = q0w + mi * 16 + (lane & 15);
#pragma unroll
        for (int ni = 0; ni < 4; ++ni) {
          int kb = k0 + ni * 16 + ((lane >> 4) << 2);
#pragma unroll
          for (int r = 0; r < 4; ++r)
            if (kb + r > qq) s[mi][ni][r] = -1e30f;
        }
      }
    }
    // row max: 15 in-lane fmax + 2 shuffles (S^T: q = lane&15)
    float rmx[2];
#pragma unroll
    for (int mi = 0; mi < 2; ++mi) {
      f32x4 t;
#pragma unroll
      for (int r = 0; r < 4; ++r)
        t[r] = fmaxf(fmaxf(s[mi][0][r], s[mi][1][r]), fmaxf(s[mi][2][r], s[mi][3][r]));
      float mx = fmaxf(fmaxf(t[0], t[1]), fmaxf(t[2], t[3]));
      mx = fmaxf(mx, __shfl_xor(mx, 16, 64));
      mx = fmaxf(mx, __shfl_xor(mx, 32, 64));
      rmx[mi] = mx;
    }
    // defer-max: rescale only when max grew past threshold (log2 domain)
    bool need = (rmx[0] > mrow[0] + 8.0f) || (rmx[1] > mrow[1] + 8.0f);
    if (__any(need)) {
#pragma unroll
      for (int mi = 0; mi < 2; ++mi) {
        float mn = fmaxf(mrow[mi], rmx[mi]);
        float al = exp2f(mrow[mi] - mn);
        mrow[mi] = mn;
        float ar[4];
#pragma unroll
        for (int r = 0; r < 4; ++r) ar[r] = __shfl(al, ((lane >> 4) << 2) + r, 64);
#pragma unroll
        for (int ni = 0; ni < 5; ++ni)
#pragma unroll
          for (int r = 0; r < 4; ++r) accO[mi][ni][r] *= ar[r];
      }
    }
    // P = exp2(s - m), truncate to bf16, pack pairs (consecutive k), b64 store
#pragma unroll
    for (int mi = 0; mi < 2; ++mi) {
      int row = mi * 16 + (lane & 15);
      int rbase = row * 128;
      int sw = (row & 7) << 4;
#pragma unroll
      for (int ni = 0; ni < 4; ++ni) {
        unsigned u0 = __float_as_uint(exp2f(s[mi][ni][0] - mrow[mi]));
        unsigned u1 = __float_as_uint(exp2f(s[mi][ni][1] - mrow[mi]));
        unsigned u2 = __float_as_uint(exp2f(s[mi][ni][2] - mrow[mi]));
        unsigned u3 = __float_as_uint(exp2f(s[mi][ni][3] - mrow[mi]));
        uint2 pk;
        pk.x = (u0 >> 16) | (u1 & 0xFFFF0000u);
        pk.y = (u2 >> 16) | (u3 & 0xFFFF0000u);
        int cb = ni * 32 + ((lane >> 4) << 3);
        *(uint2*)(PshB + rbase + (cb ^ sw)) = pk;
      }
    }
    asm volatile("" ::: "memory");  // order P writes before P reads (wave-local)
    // PV: O += P(A) x V(B); l += P x ones
#pragma unroll
    for (int ks = 0; ks < 2; ++ks) {
      bf16x8 pf[2];
#pragma unroll
      for (int mi = 0; mi < 2; ++mi) {
        int row = mi * 16 + (lane & 15);
        int cb = ks * 64 + ((lane >> 4) << 4);
        pf[mi] = *(const bf16x8*)(PshB + row * 128 + (cb ^ ((row & 7) << 4)));
      }
#pragma unroll
      for (int mi = 0; mi < 2; ++mi) {
#pragma unroll
        for (int ni = 0; ni < 4; ++ni)
          accO[mi][ni] = __builtin_amdgcn_mfma_f32_16x16x32_bf16(pf[mi], vf[ks][ni], accO[mi][ni], 0, 0, 0);
        accO[mi][4] = __builtin_amdgcn_mfma_f32_16x16x32_bf16(pf[mi], vone, accO[mi][4], 0, 0, 0);
      }
    }
#pragma unroll
    for (int ks = 0; ks < 2; ++ks)
#pragma unroll
      for (int ni = 0; ni < 4; ++ni) kfA[ks][ni] = kfB[ks][ni];
  }

  // publish per-wave state; wave0 merges
  if ((lane >> 4) == 0) {
    MR[w][lane] = mrow[0];
    MR[w][16 + lane] = mrow[1];
  }
  if (w == 1) {
#pragma unroll
    for (int mi = 0; mi < 2; ++mi) {
#pragma unroll
      for (int r = 0; r < 4; ++r) {
        int rq = mi * 16 + ((lane >> 4) << 2) + r;
#pragma unroll
        for (int ni = 0; ni < 4; ++ni)
          MO[rq][ni * 16 + (lane & 15)] = accO[mi][ni][r];
        if ((lane & 15) == 0) MO[rq][64] = accO[mi][4][r];
      }
    }
  }
  __syncthreads();
  if (w == 0) {
#pragma unroll
    for (int mi = 0; mi < 2; ++mi) {
#pragma unroll
      for (int r = 0; r < 4; ++r) {
        int rq = mi * 16 + ((lane >> 4) << 2) + r;
        float m1 = MR[0][rq], m2 = MR[1][rq];
        float M = fmaxf(m1, m2);
        float a1 = exp2f(m1 - M), a2 = exp2f(m2 - M);
        float denom = a1 * accO[mi][4][r] + a2 * MO[rq][64];
        float inv = 1.0f / denom;
        int t = q0w + rq;
#pragma unroll
        for (int ni = 0; ni < 4; ++ni) {
          int dh = ni * 16 + (lane & 15);
          float o = a1 * accO[mi][ni][r] + a2 * MO[rq][dh];
          AO[(size_t)t * DD + h * DK + dh] = f2bf(o * inv);
        }
      }
    }
  }
}

// ---------------- output projection + bias (f32 out) ----------------
__global__ __launch_bounds__(256) void gemm_o(
    const unsigned short* __restrict__ A, const unsigned short* __restrict__ W,
    const float* __restrict__ bias, float* __restrict__ out) {
  __shared__ unsigned short Ash[128 * 64];
  __shared__ unsigned short Bsh[128 * 64];
  const int brow = blockIdx.x * 128;
  const int bcol = blockIdx.y * 128;
  const int tid = threadIdx.x;
  const int lane = tid & 63;
  const int w = tid >> 6;
  const int wr = w >> 1, wc = w & 1;
  const char* Ab = (const char*)A + (size_t)brow * (DD * 2);
  const char* Wb = (const char*)W + (size_t)bcol * (DD * 2);
  char* AshB = (char*)Ash;
  char* BshB = (char*)Bsh;
  f32x4 acc[4][4];
#pragma unroll
  for (int mi = 0; mi < 4; ++mi)
#pragma unroll
    for (int ni = 0; ni < 4; ++ni)
#pragma unroll
      for (int r = 0; r < 4; ++r) acc[mi][ni][r] = 0.0f;

  for (int k0 = 0; k0 < DD; k0 += 64) {
    __syncthreads();
#pragma unroll
    for (int it = 0; it < 4; ++it) {
      int c = it * 256 + tid;
      int row = c >> 3;
      int xb = (c & 7) << 4;
      int sxb = xb ^ ((row & 7) << 4);
      int ldso = (it * 256 + (tid & 192)) << 4;
      gload16(Ab + (size_t)row * (DD * 2) + k0 * 2 + sxb, AshB + ldso);
      gload16(Wb + (size_t)row * (DD * 2) + k0 * 2 + sxb, BshB + ldso);
    }
    __syncthreads();
#pragma unroll
    for (int ks = 0; ks < 2; ++ks) {
      bf16x8 af[4], bfr[4];
      int colb = ks * 64 + ((lane >> 4) << 4);
#pragma unroll
      for (int mi = 0; mi < 4; ++mi) {
        int row = wr * 64 + mi * 16 + (lane & 15);
        af[mi] = *(const bf16x8*)(AshB + row * 128 + (colb ^ ((row & 7) << 4)));
      }
#pragma unroll
      for (int ni = 0; ni < 4; ++ni) {
        int row = wc * 64 + ni * 16 + (lane & 15);
        bfr[ni] = *(const bf16x8*)(BshB + row * 128 + (colb ^ ((row & 7) << 4)));
      }
#pragma unroll
      for (int mi = 0; mi < 4; ++mi)
#pragma unroll
        for (int ni = 0; ni < 4; ++ni)
          acc[mi][ni] = __builtin_amdgcn_mfma_f32_16x16x32_bf16(af[mi], bfr[ni], acc[mi][ni], 0, 0, 0);
    }
  }
#pragma unroll
  for (int mi = 0; mi < 4; ++mi)
#pragma unroll
    for (int r = 0; r < 4; ++r) {
      int t = brow + wr * 64 + mi * 16 + ((lane >> 4) << 2) + r;
#pragma unroll
      for (int ni = 0; ni < 4; ++ni) {
        int o = bcol + wc * 64 + ni * 16 + (lane & 15);
        out[(size_t)t * DD + o] = acc[mi][ni][r] + bias[o];
      }
    }
}

// ---------------- launch ----------------
extern "C" void kernel_launch(void* const* d_in, const int* in_sizes, int n_in,
                              void* d_out, int out_size, void* d_ws, size_t ws_size,
                              hipStream_t stream) {
  const float* q  = (const float*)d_in[0];
  const float* k  = (const float*)d_in[1];
  const float* v  = (const float*)d_in[2];
  const int* pos  = (const int*)d_in[3];
  const float* wq = (const float*)d_in[4];
  const float* wk = (const float*)d_in[5];
  const float* wv = (const float*)d_in[6];
  const float* wo = (const float*)d_in[7];
  const float* wob = (const float*)d_in[8];
  float* out = (float*)d_out;
  char* ws = (char*)d_ws;

  const size_t MB = 1u << 20;
  unsigned short* XQ = (unsigned short*)(ws + 0 * MB);
  unsigned short* XK = (unsigned short*)(ws + 4 * MB);
  unsigned short* XV = (unsigned short*)(ws + 8 * MB);
  unsigned short* WQ = (unsigned short*)(ws + 12 * MB);
  unsigned short* WK = (unsigned short*)(ws + 14 * MB);
  unsigned short* WV = (unsigned short*)(ws + 16 * MB);
  unsigned short* WO = (unsigned short*)(ws + 18 * MB);
  unsigned short* QH = (unsigned short*)(ws + 20 * MB);
  unsigned short* KH = (unsigned short*)(ws + 24 * MB);
  unsigned short* VT = (unsigned short*)(ws + 28 * MB);
  unsigned short* AOb = (unsigned short*)(ws + 32 * MB);
  float* COS = (float*)(ws + 36 * MB);
  float* SIN = (float*)(ws + 36 * MB + 262144);

  hipLaunchKernelGGL(cvt_all, dim3(5120), dim3(256), 0, stream,
                     q, k, v, wq, wk, wv, wo, XQ, XK, XV, WQ, WK, WV, WO);
  hipLaunchKernelGGL(rope_tab, dim3(256), dim3(256), 0, stream, pos, COS, SIN);
  hipLaunchKernelGGL(gemm_qkv, dim3(16, 8, 3), dim3(256), 0, stream,
                     XQ, XK, XV, WQ, WK, WV, QH, KH, VT, COS, SIN);
  hipLaunchKernelGGL(attn_fa, dim3(1024), dim3(128), 0, stream, QH, KH, VT, AOb);
  hipLaunchKernelGGL(gemm_o, dim3(16, 8), dim3(256), 0, stream, AOb, WO, wob, out);
}

// Round 5
// 109.707 us; speedup vs baseline: 1.5157x; 1.0079x over previous
//
#include <hip/hip_runtime.h>
#include <hip/hip_bf16.h>
#include <stdint.h>

#define TT 2048
#define DD 1024
#define NH 16
#define DK 64

typedef __attribute__((ext_vector_type(8))) short bf16x8;
typedef __attribute__((ext_vector_type(4))) float f32x4;
typedef __attribute__((ext_vector_type(8))) unsigned short u16x8;
typedef __attribute__((ext_vector_type(4))) unsigned short u16x4;

__device__ __forceinline__ unsigned short f2bf(float f) {
  union { float f; unsigned u; } x; x.f = f;
  unsigned r = (x.u + 0x7FFFu + ((x.u >> 16) & 1u)) >> 16;
  return (unsigned short)r;
}

__device__ __forceinline__ void gload16(const void* g, void* l) {
  __builtin_amdgcn_global_load_lds(
      (const __attribute__((address_space(1))) unsigned int*)g,
      (__attribute__((address_space(3))) unsigned int*)l, 16, 0, 0);
}

// ---------------- convert f32 -> bf16 ----------------
__global__ __launch_bounds__(256) void cvt_all(
    const float* __restrict__ q, const float* __restrict__ k, const float* __restrict__ v,
    const float* __restrict__ wq, const float* __restrict__ wk, const float* __restrict__ wv,
    const float* __restrict__ wo,
    unsigned short* __restrict__ oq, unsigned short* __restrict__ ok, unsigned short* __restrict__ ov,
    unsigned short* __restrict__ owq, unsigned short* __restrict__ owk, unsigned short* __restrict__ owv,
    unsigned short* __restrict__ owo) {
  int b = blockIdx.x;
  const float* src; unsigned short* dst; int sb;
  if (b < 1024)      { src = q;  dst = oq;  sb = b; }
  else if (b < 2048) { src = k;  dst = ok;  sb = b - 1024; }
  else if (b < 3072) { src = v;  dst = ov;  sb = b - 2048; }
  else if (b < 3584) { src = wq; dst = owq; sb = b - 3072; }
  else if (b < 4096) { src = wk; dst = owk; sb = b - 3584; }
  else if (b < 4608) { src = wv; dst = owv; sb = b - 4096; }
  else               { src = wo; dst = owo; sb = b - 4608; }
  size_t i0 = (size_t)sb * 2048 + (size_t)threadIdx.x * 8;
  f32x4 a = *(const f32x4*)(src + i0);
  f32x4 c = *(const f32x4*)(src + i0 + 4);
  u16x8 r;
#pragma unroll
  for (int j = 0; j < 4; ++j) { r[j] = f2bf(a[j]); r[j + 4] = f2bf(c[j]); }
  *(u16x8*)(dst + i0) = r;
}

// ---------------- RoPE cos/sin table ----------------
__global__ __launch_bounds__(256) void rope_tab(const int* __restrict__ pos,
                                                float* __restrict__ cosT,
                                                float* __restrict__ sinT) {
  int idx = blockIdx.x * 256 + threadIdx.x;  // 2048*32
  int t = idx >> 5, i = idx & 31;
  float inv = exp2f((float)i * -0.41524101186092028f);  // 10000^(-i/32)
  float ang = (float)pos[t] * inv;
  cosT[idx] = cosf(ang);
  sinT[idx] = sinf(ang);
}

// ---------------- fused QKV projection + RoPE ----------------
__global__ __launch_bounds__(256) void gemm_qkv(
    const unsigned short* __restrict__ xq, const unsigned short* __restrict__ xk,
    const unsigned short* __restrict__ xv,
    const unsigned short* __restrict__ wqb, const unsigned short* __restrict__ wkb,
    const unsigned short* __restrict__ wvb,
    unsigned short* __restrict__ Qh, unsigned short* __restrict__ Kh,
    unsigned short* __restrict__ Vt,
    const float* __restrict__ cosT, const float* __restrict__ sinT) {
  __shared__ unsigned short Ash[128 * 64];
  __shared__ unsigned short Bsh[128 * 64];
  const int z = blockIdx.z;
  const unsigned short* A = (z == 0) ? xq : (z == 1) ? xk : xv;
  const unsigned short* W = (z == 0) ? wqb : (z == 1) ? wkb : wvb;
  const int brow = blockIdx.x * 128;
  const int bcol = blockIdx.y * 128;
  const int tid = threadIdx.x;
  const int lane = tid & 63;
  const int w = tid >> 6;
  const int wr = w >> 1, wc = w & 1;
  const char* Ab = (const char*)A + (size_t)brow * (DD * 2);
  const char* Wb = (const char*)W + (size_t)bcol * (DD * 2);
  char* AshB = (char*)Ash;
  char* BshB = (char*)Bsh;
  f32x4 acc[4][4];
#pragma unroll
  for (int mi = 0; mi < 4; ++mi)
#pragma unroll
    for (int ni = 0; ni < 4; ++ni)
#pragma unroll
      for (int r = 0; r < 4; ++r) acc[mi][ni][r] = 0.0f;

  for (int k0 = 0; k0 < DD; k0 += 64) {
    __syncthreads();
#pragma unroll
    for (int it = 0; it < 4; ++it) {
      int c = it * 256 + tid;
      int row = c >> 3;
      int xb = (c & 7) << 4;
      int sxb = xb ^ ((row & 7) << 4);
      int ldso = (it * 256 + (tid & 192)) << 4;
      gload16(Ab + (size_t)row * (DD * 2) + k0 * 2 + sxb, AshB + ldso);
      gload16(Wb + (size_t)row * (DD * 2) + k0 * 2 + sxb, BshB + ldso);
    }
    __syncthreads();
#pragma unroll
    for (int ks = 0; ks < 2; ++ks) {
      bf16x8 af[4], bfr[4];
      int colb = ks * 64 + ((lane >> 4) << 4);
#pragma unroll
      for (int mi = 0; mi < 4; ++mi) {
        int row = wr * 64 + mi * 16 + (lane & 15);
        af[mi] = *(const bf16x8*)(AshB + row * 128 + (colb ^ ((row & 7) << 4)));
      }
#pragma unroll
      for (int ni = 0; ni < 4; ++ni) {
        int row = wc * 64 + ni * 16 + (lane & 15);
        bfr[ni] = *(const bf16x8*)(BshB + row * 128 + (colb ^ ((row & 7) << 4)));
      }
#pragma unroll
      for (int mi = 0; mi < 4; ++mi)
#pragma unroll
        for (int ni = 0; ni < 4; ++ni)
          acc[mi][ni] = __builtin_amdgcn_mfma_f32_16x16x32_bf16(af[mi], bfr[ni], acc[mi][ni], 0, 0, 0);
    }
  }

  const int hcol = bcol + wc * 64;
  const int h = hcol >> 6;
  if (z < 2) {
    unsigned short* OUT = (z == 0) ? Qh : Kh;
    // Q scale: 1/sqrt(64) * log2(e)  (scores land in log2 domain -> exp2 softmax)
    const float sc = (z == 0) ? 0.18033688011112042f : 1.0f;
#pragma unroll
    for (int mi = 0; mi < 4; ++mi) {
#pragma unroll
      for (int r = 0; r < 4; ++r) {
        int t = brow + wr * 64 + mi * 16 + ((lane >> 4) << 2) + r;
#pragma unroll
        for (int ni = 0; ni < 2; ++ni) {
          int dl = ni * 16 + (lane & 15);
          float cv = cosT[t * 32 + dl];
          float sv = sinT[t * 32 + dl];
          float x1 = acc[mi][ni][r];
          float x2 = acc[mi][ni + 2][r];
          size_t base = ((size_t)h * TT + t) * DK + dl;
          OUT[base] = f2bf((x1 * cv - x2 * sv) * sc);
          OUT[base + 32] = f2bf((x2 * cv + x1 * sv) * sc);
        }
      }
    }
  } else {
#pragma unroll
    for (int mi = 0; mi < 4; ++mi) {
#pragma unroll
      for (int ni = 0; ni < 4; ++ni) {
        int dh = ni * 16 + (lane & 15);
        int t0 = brow + wr * 64 + mi * 16 + ((lane >> 4) << 2);
        u16x4 pk;
#pragma unroll
        for (int r = 0; r < 4; ++r) pk[r] = f2bf(acc[mi][ni][r]);
        *(u16x4*)((char*)Vt + (((size_t)h * DK + dh) * TT + t0) * 2) = pk;
      }
    }
  }
}

// ---------------- causal flash attention ----------------
// grid 1024: job (h, qw). 4 waves split k-tiles mod 4 (max 8 serial tiles),
// 4-way LDS combine at end. Swapped QK^T, defer-max, l via ones-MFMA.
// bid&7 pins 2 heads per XCD; jobs issued biggest-first (qw descending).
__device__ __forceinline__ void load_kfrag(const char* Kb, int k0, int lane,
                                           bf16x8 kf[2][4]) {
#pragma unroll
  for (int ks = 0; ks < 2; ++ks)
#pragma unroll
    for (int ni = 0; ni < 4; ++ni) {
      const char* p = Kb + (size_t)(k0 + ni * 16 + (lane & 15)) * 128 + ks * 64 +
                      ((lane >> 4) << 4);
      kf[ks][ni] = *(const bf16x8*)p;
    }
}

__device__ __forceinline__ void load_vfrag(const char* Vb, int k0, int lane,
                                           bf16x8 vf[2][4]) {
#pragma unroll
  for (int ks = 0; ks < 2; ++ks)
#pragma unroll
    for (int ni = 0; ni < 4; ++ni) {
      const char* p = Vb + (size_t)(ni * 16 + (lane & 15)) * (TT * 2) +
                      (k0 + ks * 32) * 2 + ((lane >> 4) << 4);
      vf[ks][ni] = *(const bf16x8*)p;
    }
}

__global__ __launch_bounds__(256) void attn_fa(
    const unsigned short* __restrict__ Qh, const unsigned short* __restrict__ Kh,
    const unsigned short* __restrict__ Vt, unsigned short* __restrict__ AO) {
  // LB: per-wave P buffers (4 x 4KB) during loop; MO partials (3*32*68*4B) after
  __shared__ char LB[26624];
  __shared__ float MR[4][32];
  const int tid = threadIdx.x;
  const int lane = tid & 63;
  const int w = tid >> 6;
  const int bid = blockIdx.x;
  const int xcd = bid & 7;
  const int idx = bid >> 3;          // 128 jobs per XCD
  const int h = xcd * 2 + (idx & 1); // 2 heads pinned per XCD
  const int qw = 63 - (idx >> 1);    // biggest jobs dispatch first
  const int q0w = qw * 32;
  const int NT = (qw >> 1) + 1;
  char* PshB = LB + w * 4096;
  const char* Kb = (const char*)Kh + (size_t)h * TT * DK * 2;
  const char* Vb = (const char*)Vt + (size_t)h * DK * TT * 2;

  // Q fragments (B-operand for swapped QK^T)
  bf16x8 qf[2][2];
#pragma unroll
  for (int mi = 0; mi < 2; ++mi)
#pragma unroll
    for (int ks = 0; ks < 2; ++ks) {
      const unsigned short* p =
          Qh + ((size_t)h * TT + q0w + mi * 16 + (lane & 15)) * DK + ks * 32 + ((lane >> 4) << 3);
      qf[mi][ks] = *(const bf16x8*)p;
    }

  bf16x8 vone;
#pragma unroll
  for (int j = 0; j < 8; ++j) vone[j] = (short)0x3F80;  // bf16 1.0

  f32x4 accO[2][5];  // [..][4] = row-sum l (ones-column MFMA)
  float mrow[2];
#pragma unroll
  for (int mi = 0; mi < 2; ++mi) {
    mrow[mi] = -1e30f;
#pragma unroll
    for (int ni = 0; ni < 5; ++ni)
#pragma unroll
      for (int r = 0; r < 4; ++r) accO[mi][ni][r] = 0.0f;
  }

  bf16x8 kfA[2][4], kfB[2][4], vf[2][4];
  {
    int kt0 = (w < NT) ? w : 0;
    load_kfrag(Kb, kt0 * 64, lane, kfA);
  }

  for (int kt = w; kt < NT; kt += 4) {
    const int k0 = kt * 64;
    load_vfrag(Vb, k0, lane, vf);  // issue early; QK+softmax hides latency
    f32x4 s[2][4];
#pragma unroll
    for (int mi = 0; mi < 2; ++mi)
#pragma unroll
      for (int ni = 0; ni < 4; ++ni)
#pragma unroll
        for (int r = 0; r < 4; ++r) s[mi][ni][r] = 0.0f;
    // swapped: S^T[k][q] = K-frag (A) x Q-frag (B); row=k, col=q
    __builtin_amdgcn_s_setprio(1);
#pragma unroll
    for (int ks = 0; ks < 2; ++ks)
#pragma unroll
      for (int mi = 0; mi < 2; ++mi)
#pragma unroll
        for (int ni = 0; ni < 4; ++ni)
          s[mi][ni] = __builtin_amdgcn_mfma_f32_16x16x32_bf16(kfA[ks][ni], qf[mi][ks], s[mi][ni], 0, 0, 0);
    __builtin_amdgcn_s_setprio(0);
    if (kt + 4 < NT) load_kfrag(Kb, k0 + 256, lane, kfB);  // prefetch own next

    if (kt == NT - 1) {  // diagonal tile: causal mask
#pragma unroll
      for (int mi = 0; mi < 2; ++mi) {
        int qq = q0w + mi * 16 + (lane & 15);
#pragma unroll
        for (int ni = 0; ni < 4; ++ni) {
          int kb = k0 + ni * 16 + ((lane >> 4) << 2);
#pragma unroll
          for (int r = 0; r < 4; ++r)
            if (kb + r > qq) s[mi][ni][r] = -1e30f;
        }
      }
    }
    // row max: 15 in-lane fmax + 2 shuffles (S^T: q = lane&15)
    float rmx[2];
#pragma unroll
    for (int mi = 0; mi < 2; ++mi) {
      f32x4 t;
#pragma unroll
      for (int r = 0; r < 4; ++r)
        t[r] = fmaxf(fmaxf(s[mi][0][r], s[mi][1][r]), fmaxf(s[mi][2][r], s[mi][3][r]));
      float mx = fmaxf(fmaxf(t[0], t[1]), fmaxf(t[2], t[3]));
      mx = fmaxf(mx, __shfl_xor(mx, 16, 64));
      mx = fmaxf(mx, __shfl_xor(mx, 32, 64));
      rmx[mi] = mx;
    }
    // defer-max: rescale only when max grew past threshold (log2 domain)
    bool need = (rmx[0] > mrow[0] + 8.0f) || (rmx[1] > mrow[1] + 8.0f);
    if (__any(need)) {
#pragma unroll
      for (int mi = 0; mi < 2; ++mi) {
        float mn = fmaxf(mrow[mi], rmx[mi]);
        float al = exp2f(mrow[mi] - mn);
        mrow[mi] = mn;
        float ar[4];
#pragma unroll
        for (int r = 0; r < 4; ++r) ar[r] = __shfl(al, ((lane >> 4) << 2) + r, 64);
#pragma unroll
        for (int ni = 0; ni < 5; ++ni)
#pragma unroll
          for (int r = 0; r < 4; ++r) accO[mi][ni][r] *= ar[r];
      }
    }
    // P = exp2(s - m), truncate to bf16, pack pairs (consecutive k), b64 store
#pragma unroll
    for (int mi = 0; mi < 2; ++mi) {
      int row = mi * 16 + (lane & 15);
      int rbase = row * 128;
      int sw = (row & 7) << 4;
#pragma unroll
      for (int ni = 0; ni < 4; ++ni) {
        unsigned u0 = __float_as_uint(exp2f(s[mi][ni][0] - mrow[mi]));
        unsigned u1 = __float_as_uint(exp2f(s[mi][ni][1] - mrow[mi]));
        unsigned u2 = __float_as_uint(exp2f(s[mi][ni][2] - mrow[mi]));
        unsigned u3 = __float_as_uint(exp2f(s[mi][ni][3] - mrow[mi]));
        uint2 pk;
        pk.x = (u0 >> 16) | (u1 & 0xFFFF0000u);
        pk.y = (u2 >> 16) | (u3 & 0xFFFF0000u);
        int cb = ni * 32 + ((lane >> 4) << 3);
        *(uint2*)(PshB + rbase + (cb ^ sw)) = pk;
      }
    }
    asm volatile("" ::: "memory");  // order P writes before P reads (wave-local)
    // PV: O += P(A) x V(B); l += P x ones
    __builtin_amdgcn_s_setprio(1);
#pragma unroll
    for (int ks = 0; ks < 2; ++ks) {
      bf16x8 pf[2];
#pragma unroll
      for (int mi = 0; mi < 2; ++mi) {
        int row = mi * 16 + (lane & 15);
        int cb = ks * 64 + ((lane >> 4) << 4);
        pf[mi] = *(const bf16x8*)(PshB + row * 128 + (cb ^ ((row & 7) << 4)));
      }
#pragma unroll
      for (int mi = 0; mi < 2; ++mi) {
#pragma unroll
        for (int ni = 0; ni < 4; ++ni)
          accO[mi][ni] = __builtin_amdgcn_mfma_f32_16x16x32_bf16(pf[mi], vf[ks][ni], accO[mi][ni], 0, 0, 0);
        accO[mi][4] = __builtin_amdgcn_mfma_f32_16x16x32_bf16(pf[mi], vone, accO[mi][4], 0, 0, 0);
      }
    }
    __builtin_amdgcn_s_setprio(0);
#pragma unroll
    for (int ks = 0; ks < 2; ++ks)
#pragma unroll
      for (int ni = 0; ni < 4; ++ni) kfA[ks][ni] = kfB[ks][ni];
  }

  __syncthreads();  // all waves done with P buffers; LB becomes MO partials
  if ((lane >> 4) == 0) {
    MR[w][lane] = mrow[0];
    MR[w][16 + lane] = mrow[1];
  }
  if (w > 0) {
    float* MOw = (float*)LB + (size_t)(w - 1) * 32 * 68;
#pragma unroll
    for (int mi = 0; mi < 2; ++mi) {
#pragma unroll
      for (int r = 0; r < 4; ++r) {
        int rq = mi * 16 + ((lane >> 4) << 2) + r;
#pragma unroll
        for (int ni = 0; ni < 4; ++ni)
          MOw[rq * 68 + ni * 16 + (lane & 15)] = accO[mi][ni][r];
        if ((lane & 15) == 0) MOw[rq * 68 + 64] = accO[mi][4][r];
      }
    }
  }
  __syncthreads();
  if (w == 0) {
    const float* MOp = (const float*)LB;
#pragma unroll
    for (int mi = 0; mi < 2; ++mi) {
#pragma unroll
      for (int r = 0; r < 4; ++r) {
        int rq = mi * 16 + ((lane >> 4) << 2) + r;
        float m0 = MR[0][rq], m1 = MR[1][rq], m2 = MR[2][rq], m3 = MR[3][rq];
        float M = fmaxf(fmaxf(m0, m1), fmaxf(m2, m3));
        float a0 = exp2f(m0 - M), a1 = exp2f(m1 - M);
        float a2 = exp2f(m2 - M), a3 = exp2f(m3 - M);
        float denom = a0 * accO[mi][4][r] + a1 * MOp[(0 * 32 + rq) * 68 + 64] +
                      a2 * MOp[(1 * 32 + rq) * 68 + 64] + a3 * MOp[(2 * 32 + rq) * 68 + 64];
        float inv = 1.0f / denom;
        int t = q0w + rq;
#pragma unroll
        for (int ni = 0; ni < 4; ++ni) {
          int dh = ni * 16 + (lane & 15);
          float o = a0 * accO[mi][ni][r] + a1 * MOp[(0 * 32 + rq) * 68 + dh] +
                    a2 * MOp[(1 * 32 + rq) * 68 + dh] + a3 * MOp[(2 * 32 + rq) * 68 + dh];
          AO[(size_t)t * DD + h * DK + dh] = f2bf(o * inv);
        }
      }
    }
  }
}

// ---------------- output projection + bias (f32 out) ----------------
__global__ __launch_bounds__(256) void gemm_o(
    const unsigned short* __restrict__ A, const unsigned short* __restrict__ W,
    const float* __restrict__ bias, float* __restrict__ out) {
  __shared__ unsigned short Ash[128 * 64];
  __shared__ unsigned short Bsh[128 * 64];
  const int brow = blockIdx.x * 128;
  const int bcol = blockIdx.y * 128;
  const int tid = threadIdx.x;
  const int lane = tid & 63;
  const int w = tid >> 6;
  const int wr = w >> 1, wc = w & 1;
  const char* Ab = (const char*)A + (size_t)brow * (DD * 2);
  const char* Wb = (const char*)W + (size_t)bcol * (DD * 2);
  char* AshB = (char*)Ash;
  char* BshB = (char*)Bsh;
  f32x4 acc[4][4];
#pragma unroll
  for (int mi = 0; mi < 4; ++mi)
#pragma unroll
    for (int ni = 0; ni < 4; ++ni)
#pragma unroll
      for (int r = 0; r < 4; ++r) acc[mi][ni][r] = 0.0f;

  for (int k0 = 0; k0 < DD; k0 += 64) {
    __syncthreads();
#pragma unroll
    for (int it = 0; it < 4; ++it) {
      int c = it * 256 + tid;
      int row = c >> 3;
      int xb = (c & 7) << 4;
      int sxb = xb ^ ((row & 7) << 4);
      int ldso = (it * 256 + (tid & 192)) << 4;
      gload16(Ab + (size_t)row * (DD * 2) + k0 * 2 + sxb, AshB + ldso);
      gload16(Wb + (size_t)row * (DD * 2) + k0 * 2 + sxb, BshB + ldso);
    }
    __syncthreads();
#pragma unroll
    for (int ks = 0; ks < 2; ++ks) {
      bf16x8 af[4], bfr[4];
      int colb = ks * 64 + ((lane >> 4) << 4);
#pragma unroll
      for (int mi = 0; mi < 4; ++mi) {
        int row = wr * 64 + mi * 16 + (lane & 15);
        af[mi] = *(const bf16x8*)(AshB + row * 128 + (colb ^ ((row & 7) << 4)));
      }
#pragma unroll
      for (int ni = 0; ni < 4; ++ni) {
        int row = wc * 64 + ni * 16 + (lane & 15);
        bfr[ni] = *(const bf16x8*)(BshB + row * 128 + (colb ^ ((row & 7) << 4)));
      }
#pragma unroll
      for (int mi = 0; mi < 4; ++mi)
#pragma unroll
        for (int ni = 0; ni < 4; ++ni)
          acc[mi][ni] = __builtin_amdgcn_mfma_f32_16x16x32_bf16(af[mi], bfr[ni], acc[mi][ni], 0, 0, 0);
    }
  }
#pragma unroll
  for (int mi = 0; mi < 4; ++mi)
#pragma unroll
    for (int r = 0; r < 4; ++r) {
      int t = brow + wr * 64 + mi * 16 + ((lane >> 4) << 2) + r;
#pragma unroll
      for (int ni = 0; ni < 4; ++ni) {
        int o = bcol + wc * 64 + ni * 16 + (lane & 15);
        out[(size_t)t * DD + o] = acc[mi][ni][r] + bias[o];
      }
    }
}

// ---------------- launch ----------------
extern "C" void kernel_launch(void* const* d_in, const int* in_sizes, int n_in,
                              void* d_out, int out_size, void* d_ws, size_t ws_size,
                              hipStream_t stream) {
  const float* q  = (const float*)d_in[0];
  const float* k  = (const float*)d_in[1];
  const float* v  = (const float*)d_in[2];
  const int* pos  = (const int*)d_in[3];
  const float* wq = (const float*)d_in[4];
  const float* wk = (const float*)d_in[5];
  const float* wv = (const float*)d_in[6];
  const float* wo = (const float*)d_in[7];
  const float* wob = (const float*)d_in[8];
  float* out = (float*)d_out;
  char* ws = (char*)d_ws;

  const size_t MB = 1u << 20;
  unsigned short* XQ = (unsigned short*)(ws + 0 * MB);
  unsigned short* XK = (unsigned short*)(ws + 4 * MB);
  unsigned short* XV = (unsigned short*)(ws + 8 * MB);
  unsigned short* WQ = (unsigned short*)(ws + 12 * MB);
  unsigned short* WK = (unsigned short*)(ws + 14 * MB);
  unsigned short* WV = (unsigned short*)(ws + 16 * MB);
  unsigned short* WO = (unsigned short*)(ws + 18 * MB);
  unsigned short* QH = (unsigned short*)(ws + 20 * MB);
  unsigned short* KH = (unsigned short*)(ws + 24 * MB);
  unsigned short* VT = (unsigned short*)(ws + 28 * MB);
  unsigned short* AOb = (unsigned short*)(ws + 32 * MB);
  float* COS = (float*)(ws + 36 * MB);
  float* SIN = (float*)(ws + 36 * MB + 262144);

  hipLaunchKernelGGL(cvt_all, dim3(5120), dim3(256), 0, stream,
                     q, k, v, wq, wk, wv, wo, XQ, XK, XV, WQ, WK, WV, WO);
  hipLaunchKernelGGL(rope_tab, dim3(256), dim3(256), 0, stream, pos, COS, SIN);
  hipLaunchKernelGGL(gemm_qkv, dim3(16, 8, 3), dim3(256), 0, stream,
                     XQ, XK, XV, WQ, WK, WV, QH, KH, VT, COS, SIN);
  hipLaunchKernelGGL(attn_fa, dim3(1024), dim3(256), 0, stream, QH, KH, VT, AOb);
  hipLaunchKernelGGL(gemm_o, dim3(16, 8), dim3(256), 0, stream, AOb, WO, wob, out);
}

// Round 6
// 100.788 us; speedup vs baseline: 1.6498x; 1.0885x over previous
//
#include <hip/hip_runtime.h>
#include <hip/hip_bf16.h>
#include <stdint.h>

#define TT 2048
#define DD 1024
#define NH 16
#define DK 64

typedef __attribute__((ext_vector_type(8))) short bf16x8;
typedef __attribute__((ext_vector_type(4))) float f32x4;
typedef __attribute__((ext_vector_type(8))) unsigned short u16x8;
typedef __attribute__((ext_vector_type(4))) unsigned short u16x4;

__device__ __forceinline__ unsigned short f2bf(float f) {
  union { float f; unsigned u; } x; x.f = f;
  unsigned r = (x.u + 0x7FFFu + ((x.u >> 16) & 1u)) >> 16;
  return (unsigned short)r;
}

__device__ __forceinline__ void gload16(const void* g, void* l) {
  __builtin_amdgcn_global_load_lds(
      (const __attribute__((address_space(1))) unsigned int*)g,
      (__attribute__((address_space(3))) unsigned int*)l, 16, 0, 0);
}

// ---------------- convert f32 -> bf16 ----------------
__global__ __launch_bounds__(256) void cvt_all(
    const float* __restrict__ q, const float* __restrict__ k, const float* __restrict__ v,
    const float* __restrict__ wq, const float* __restrict__ wk, const float* __restrict__ wv,
    const float* __restrict__ wo,
    unsigned short* __restrict__ oq, unsigned short* __restrict__ ok, unsigned short* __restrict__ ov,
    unsigned short* __restrict__ owq, unsigned short* __restrict__ owk, unsigned short* __restrict__ owv,
    unsigned short* __restrict__ owo) {
  int b = blockIdx.x;
  const float* src; unsigned short* dst; int sb;
  if (b < 1024)      { src = q;  dst = oq;  sb = b; }
  else if (b < 2048) { src = k;  dst = ok;  sb = b - 1024; }
  else if (b < 3072) { src = v;  dst = ov;  sb = b - 2048; }
  else if (b < 3584) { src = wq; dst = owq; sb = b - 3072; }
  else if (b < 4096) { src = wk; dst = owk; sb = b - 3584; }
  else if (b < 4608) { src = wv; dst = owv; sb = b - 4096; }
  else               { src = wo; dst = owo; sb = b - 4608; }
  size_t i0 = (size_t)sb * 2048 + (size_t)threadIdx.x * 8;
  f32x4 a = *(const f32x4*)(src + i0);
  f32x4 c = *(const f32x4*)(src + i0 + 4);
  u16x8 r;
#pragma unroll
  for (int j = 0; j < 4; ++j) { r[j] = f2bf(a[j]); r[j + 4] = f2bf(c[j]); }
  *(u16x8*)(dst + i0) = r;
}

// ---------------- RoPE cos/sin table ----------------
__global__ __launch_bounds__(256) void rope_tab(const int* __restrict__ pos,
                                                float* __restrict__ cosT,
                                                float* __restrict__ sinT) {
  int idx = blockIdx.x * 256 + threadIdx.x;  // 2048*32
  int t = idx >> 5, i = idx & 31;
  float inv = exp2f((float)i * -0.41524101186092028f);  // 10000^(-i/32)
  float ang = (float)pos[t] * inv;
  cosT[idx] = cosf(ang);
  sinT[idx] = sinf(ang);
}

// ---------------- fused QKV projection + RoPE ----------------
// Outputs are written in MFMA FRAGMENT-NATIVE layouts so attn loads are
// fully coalesced (base + lane*16):
//  QF[h][qw][mi][ks][lane]: Q[t=qw*32+mi*16+(lane&15)][d=ks*32+(lane>>4)*8+j]
//  KF[h][kt][ks][ni][lane]: K[k=kt*64+ni*16+(lane&15)][d=ks*32+(lane>>4)*8+j]
//  VF[h][kt][ks][ni][lane]: V[k=kt*64+ks*32+(lane>>4)*8+j][d=ni*16+(lane&15)]
__global__ __launch_bounds__(256) void gemm_qkv(
    const unsigned short* __restrict__ xq, const unsigned short* __restrict__ xk,
    const unsigned short* __restrict__ xv,
    const unsigned short* __restrict__ wqb, const unsigned short* __restrict__ wkb,
    const unsigned short* __restrict__ wvb,
    unsigned short* __restrict__ QF, unsigned short* __restrict__ KF,
    unsigned short* __restrict__ VF,
    const float* __restrict__ cosT, const float* __restrict__ sinT) {
  __shared__ unsigned short Ash[128 * 64];
  __shared__ unsigned short Bsh[128 * 64];
  const int z = blockIdx.z;
  const unsigned short* A = (z == 0) ? xq : (z == 1) ? xk : xv;
  const unsigned short* W = (z == 0) ? wqb : (z == 1) ? wkb : wvb;
  const int brow = blockIdx.x * 128;
  const int bcol = blockIdx.y * 128;
  const int tid = threadIdx.x;
  const int lane = tid & 63;
  const int w = tid >> 6;
  const int wr = w >> 1, wc = w & 1;
  const char* Ab = (const char*)A + (size_t)brow * (DD * 2);
  const char* Wb = (const char*)W + (size_t)bcol * (DD * 2);
  char* AshB = (char*)Ash;
  char* BshB = (char*)Bsh;
  f32x4 acc[4][4];
#pragma unroll
  for (int mi = 0; mi < 4; ++mi)
#pragma unroll
    for (int ni = 0; ni < 4; ++ni)
#pragma unroll
      for (int r = 0; r < 4; ++r) acc[mi][ni][r] = 0.0f;

  for (int k0 = 0; k0 < DD; k0 += 64) {
    __syncthreads();
#pragma unroll
    for (int it = 0; it < 4; ++it) {
      int c = it * 256 + tid;
      int row = c >> 3;
      int xb = (c & 7) << 4;
      int sxb = xb ^ ((row & 7) << 4);
      int ldso = (it * 256 + (tid & 192)) << 4;
      gload16(Ab + (size_t)row * (DD * 2) + k0 * 2 + sxb, AshB + ldso);
      gload16(Wb + (size_t)row * (DD * 2) + k0 * 2 + sxb, BshB + ldso);
    }
    __syncthreads();
#pragma unroll
    for (int ks = 0; ks < 2; ++ks) {
      bf16x8 af[4], bfr[4];
      int colb = ks * 64 + ((lane >> 4) << 4);
#pragma unroll
      for (int mi = 0; mi < 4; ++mi) {
        int row = wr * 64 + mi * 16 + (lane & 15);
        af[mi] = *(const bf16x8*)(AshB + row * 128 + (colb ^ ((row & 7) << 4)));
      }
#pragma unroll
      for (int ni = 0; ni < 4; ++ni) {
        int row = wc * 64 + ni * 16 + (lane & 15);
        bfr[ni] = *(const bf16x8*)(BshB + row * 128 + (colb ^ ((row & 7) << 4)));
      }
#pragma unroll
      for (int mi = 0; mi < 4; ++mi)
#pragma unroll
        for (int ni = 0; ni < 4; ++ni)
          acc[mi][ni] = __builtin_amdgcn_mfma_f32_16x16x32_bf16(af[mi], bfr[ni], acc[mi][ni], 0, 0, 0);
    }
  }

  const int hcol = bcol + wc * 64;
  const int h = hcol >> 6;
  if (z == 0) {
    // Q + RoPE + scale(1/8 * log2e) -> QF fragment-native
    const float sc = 0.18033688011112042f;
#pragma unroll
    for (int mi = 0; mi < 4; ++mi) {
#pragma unroll
      for (int r = 0; r < 4; ++r) {
        int t = brow + wr * 64 + mi * 16 + ((lane >> 4) << 2) + r;
        int qw_ = t >> 5, mif = (t >> 4) & 1, r16 = t & 15;
        size_t fb = (((size_t)(h * 64 + qw_) * 2 + mif) * 2) * 1024;  // bytes, ks=0
#pragma unroll
        for (int ni = 0; ni < 2; ++ni) {
          int dl = ni * 16 + (lane & 15);  // d in [0,32)
          float cv = cosT[t * 32 + dl];
          float sv = sinT[t * 32 + dl];
          float x1 = acc[mi][ni][r];
          float x2 = acc[mi][ni + 2][r];
          size_t off = fb + (size_t)(r16 + 16 * (dl >> 3)) * 16 + (dl & 7) * 2;
          *(unsigned short*)((char*)QF + off) = f2bf((x1 * cv - x2 * sv) * sc);
          *(unsigned short*)((char*)QF + off + 1024) = f2bf((x2 * cv + x1 * sv) * sc);
        }
      }
    }
  } else if (z == 1) {
    // K + RoPE -> KF fragment-native
#pragma unroll
    for (int mi = 0; mi < 4; ++mi) {
#pragma unroll
      for (int r = 0; r < 4; ++r) {
        int t = brow + wr * 64 + mi * 16 + ((lane >> 4) << 2) + r;
        int kt = t >> 6, nif = (t >> 4) & 3, r16 = t & 15;
        size_t fb = (((size_t)(h * 32 + kt) * 2) * 4 + nif) * 1024;  // bytes, ks=0
#pragma unroll
        for (int ni = 0; ni < 2; ++ni) {
          int dl = ni * 16 + (lane & 15);
          float cv = cosT[t * 32 + dl];
          float sv = sinT[t * 32 + dl];
          float x1 = acc[mi][ni][r];
          float x2 = acc[mi][ni + 2][r];
          size_t off = fb + (size_t)(r16 + 16 * (dl >> 3)) * 16 + (dl & 7) * 2;
          *(unsigned short*)((char*)KF + off) = f2bf(x1 * cv - x2 * sv);
          *(unsigned short*)((char*)KF + off + 4096) = f2bf(x2 * cv + x1 * sv);  // ks=1: +4*1024
        }
      }
    }
  } else {
    // V -> VF fragment-native
#pragma unroll
    for (int mi = 0; mi < 4; ++mi) {
      int t0 = brow + wr * 64 + mi * 16 + ((lane >> 4) << 2);
      int kt = t0 >> 6, ksf = (t0 & 63) >> 5, slot = (t0 & 31) >> 3, j0 = t0 & 7;
#pragma unroll
      for (int ni = 0; ni < 4; ++ni) {
        int dh = ni * 16 + (lane & 15);
        int lanef = (dh & 15) + 16 * slot;
        int nif = dh >> 4;
        size_t off = ((((size_t)(h * 32 + kt) * 2 + ksf) * 4 + nif) * 64 + lanef) * 16 + j0 * 2;
        u16x4 pk;
#pragma unroll
        for (int r = 0; r < 4; ++r) pk[r] = f2bf(acc[mi][ni][r]);
        *(u16x4*)((char*)VF + off) = pk;
      }
    }
  }
}

// ---------------- causal flash attention ----------------
// grid 1024: job (h, qw). 4 waves split k-tiles mod 4, 4-way LDS combine.
// Swapped QK^T, defer-max, l via ones-MFMA. All global loads coalesced
// (fragment-native layouts, base + lane*16). bid&7 pins 2 heads/XCD.
__global__ __launch_bounds__(256) void attn_fa(
    const unsigned short* __restrict__ QF, const unsigned short* __restrict__ KF,
    const unsigned short* __restrict__ VF, unsigned short* __restrict__ AO) {
  __shared__ char LB[26624];
  __shared__ float MR[4][32];
  const int tid = threadIdx.x;
  const int lane = tid & 63;
  const int w = tid >> 6;
  const int bid = blockIdx.x;
  const int xcd = bid & 7;
  const int idx = bid >> 3;          // 128 jobs per XCD
  const int h = xcd * 2 + (idx & 1); // 2 heads pinned per XCD
  const int qw = 63 - (idx >> 1);    // biggest jobs dispatch first
  const int q0w = qw * 32;
  const int NT = (qw >> 1) + 1;
  char* PshB = LB + w * 4096;
  const char* Kb = (const char*)KF + (size_t)h * 32 * 8192;  // 8KB per k-tile
  const char* Vb = (const char*)VF + (size_t)h * 32 * 8192;

  // Q fragments: coalesced
  bf16x8 qf[2][2];
  {
    const char* Qb = (const char*)QF + (size_t)(h * 64 + qw) * 4096;
#pragma unroll
    for (int mi = 0; mi < 2; ++mi)
#pragma unroll
      for (int ks = 0; ks < 2; ++ks)
        qf[mi][ks] = *(const bf16x8*)(Qb + (mi * 2 + ks) * 1024 + lane * 16);
  }

  bf16x8 vone;
#pragma unroll
  for (int j = 0; j < 8; ++j) vone[j] = (short)0x3F80;  // bf16 1.0

  f32x4 accO[2][5];  // [..][4] = row-sum l (ones-column MFMA)
  float mrow[2];
#pragma unroll
  for (int mi = 0; mi < 2; ++mi) {
    mrow[mi] = -1e30f;
#pragma unroll
    for (int ni = 0; ni < 5; ++ni)
#pragma unroll
      for (int r = 0; r < 4; ++r) accO[mi][ni][r] = 0.0f;
  }

  bf16x8 kfA[2][4], kfB[2][4], vf[2][4];
  {
    int kt0 = (w < NT) ? w : 0;
    const char* p = Kb + (size_t)kt0 * 8192 + lane * 16;
#pragma unroll
    for (int ks = 0; ks < 2; ++ks)
#pragma unroll
      for (int ni = 0; ni < 4; ++ni)
        kfA[ks][ni] = *(const bf16x8*)(p + (ks * 4 + ni) * 1024);
  }

  for (int kt = w; kt < NT; kt += 4) {
    {  // V tile: coalesced; issue early, QK+softmax hides latency
      const char* p = Vb + (size_t)kt * 8192 + lane * 16;
#pragma unroll
      for (int ks = 0; ks < 2; ++ks)
#pragma unroll
        for (int ni = 0; ni < 4; ++ni)
          vf[ks][ni] = *(const bf16x8*)(p + (ks * 4 + ni) * 1024);
    }
    f32x4 s[2][4];
#pragma unroll
    for (int mi = 0; mi < 2; ++mi)
#pragma unroll
      for (int ni = 0; ni < 4; ++ni)
#pragma unroll
        for (int r = 0; r < 4; ++r) s[mi][ni][r] = 0.0f;
    // swapped: S^T[k][q] = K-frag (A) x Q-frag (B); D col=q(lane&15), row=k
    __builtin_amdgcn_s_setprio(1);
#pragma unroll
    for (int ks = 0; ks < 2; ++ks)
#pragma unroll
      for (int mi = 0; mi < 2; ++mi)
#pragma unroll
        for (int ni = 0; ni < 4; ++ni)
          s[mi][ni] = __builtin_amdgcn_mfma_f32_16x16x32_bf16(kfA[ks][ni], qf[mi][ks], s[mi][ni], 0, 0, 0);
    __builtin_amdgcn_s_setprio(0);
    if (kt + 4 < NT) {  // prefetch own next K tile
      const char* p = Kb + (size_t)(kt + 4) * 8192 + lane * 16;
#pragma unroll
      for (int ks = 0; ks < 2; ++ks)
#pragma unroll
        for (int ni = 0; ni < 4; ++ni)
          kfB[ks][ni] = *(const bf16x8*)(p + (ks * 4 + ni) * 1024);
    }

    if (kt == NT - 1) {  // diagonal tile: causal mask
#pragma unroll
      for (int mi = 0; mi < 2; ++mi) {
        int qq = q0w + mi * 16 + (lane & 15);
#pragma unroll
        for (int ni = 0; ni < 4; ++ni) {
          int kb = kt * 64 + ni * 16 + ((lane >> 4) << 2);
#pragma unroll
          for (int r = 0; r < 4; ++r)
            if (kb + r > qq) s[mi][ni][r] = -1e30f;
        }
      }
    }
    // row max: 15 in-lane fmax + 2 shuffles (S^T: q = lane&15)
    float rmx[2];
#pragma unroll
    for (int mi = 0; mi < 2; ++mi) {
      f32x4 t;
#pragma unroll
      for (int r = 0; r < 4; ++r)
        t[r] = fmaxf(fmaxf(s[mi][0][r], s[mi][1][r]), fmaxf(s[mi][2][r], s[mi][3][r]));
      float mx = fmaxf(fmaxf(t[0], t[1]), fmaxf(t[2], t[3]));
      mx = fmaxf(mx, __shfl_xor(mx, 16, 64));
      mx = fmaxf(mx, __shfl_xor(mx, 32, 64));
      rmx[mi] = mx;
    }
    // defer-max: rescale only when max grew past threshold (log2 domain)
    bool need = (rmx[0] > mrow[0] + 8.0f) || (rmx[1] > mrow[1] + 8.0f);
    if (__any(need)) {
#pragma unroll
      for (int mi = 0; mi < 2; ++mi) {
        float mn = fmaxf(mrow[mi], rmx[mi]);
        float al = exp2f(mrow[mi] - mn);
        mrow[mi] = mn;
        float ar[4];
#pragma unroll
        for (int r = 0; r < 4; ++r) ar[r] = __shfl(al, ((lane >> 4) << 2) + r, 64);
#pragma unroll
        for (int ni = 0; ni < 5; ++ni)
#pragma unroll
          for (int r = 0; r < 4; ++r) accO[mi][ni][r] *= ar[r];
      }
    }
    // P = exp2(s - m), bf16-pack pairs (consecutive k), b64 store
#pragma unroll
    for (int mi = 0; mi < 2; ++mi) {
      int row = mi * 16 + (lane & 15);
      int rbase = row * 128;
      int sw = (row & 7) << 4;
#pragma unroll
      for (int ni = 0; ni < 4; ++ni) {
        unsigned u0 = __float_as_uint(exp2f(s[mi][ni][0] - mrow[mi]));
        unsigned u1 = __float_as_uint(exp2f(s[mi][ni][1] - mrow[mi]));
        unsigned u2 = __float_as_uint(exp2f(s[mi][ni][2] - mrow[mi]));
        unsigned u3 = __float_as_uint(exp2f(s[mi][ni][3] - mrow[mi]));
        uint2 pk;
        pk.x = (u0 >> 16) | (u1 & 0xFFFF0000u);
        pk.y = (u2 >> 16) | (u3 & 0xFFFF0000u);
        int cb = ni * 32 + ((lane >> 4) << 3);
        *(uint2*)(PshB + rbase + (cb ^ sw)) = pk;
      }
    }
    asm volatile("" ::: "memory");  // order P writes before P reads (wave-local)
    // PV: O += P(A) x V(B); l += P x ones
    __builtin_amdgcn_s_setprio(1);
#pragma unroll
    for (int ks = 0; ks < 2; ++ks) {
      bf16x8 pf[2];
#pragma unroll
      for (int mi = 0; mi < 2; ++mi) {
        int row = mi * 16 + (lane & 15);
        int cb = ks * 64 + ((lane >> 4) << 4);
        pf[mi] = *(const bf16x8*)(PshB + row * 128 + (cb ^ ((row & 7) << 4)));
      }
#pragma unroll
      for (int mi = 0; mi < 2; ++mi) {
#pragma unroll
        for (int ni = 0; ni < 4; ++ni)
          accO[mi][ni] = __builtin_amdgcn_mfma_f32_16x16x32_bf16(pf[mi], vf[ks][ni], accO[mi][ni], 0, 0, 0);
        accO[mi][4] = __builtin_amdgcn_mfma_f32_16x16x32_bf16(pf[mi], vone, accO[mi][4], 0, 0, 0);
      }
    }
    __builtin_amdgcn_s_setprio(0);
#pragma unroll
    for (int ks = 0; ks < 2; ++ks)
#pragma unroll
      for (int ni = 0; ni < 4; ++ni) kfA[ks][ni] = kfB[ks][ni];
  }

  __syncthreads();  // all waves done with P buffers; LB becomes MO partials
  if ((lane >> 4) == 0) {
    MR[w][lane] = mrow[0];
    MR[w][16 + lane] = mrow[1];
  }
  if (w > 0) {
    float* MOw = (float*)LB + (size_t)(w - 1) * 32 * 68;
#pragma unroll
    for (int mi = 0; mi < 2; ++mi) {
#pragma unroll
      for (int r = 0; r < 4; ++r) {
        int rq = mi * 16 + ((lane >> 4) << 2) + r;
#pragma unroll
        for (int ni = 0; ni < 4; ++ni)
          MOw[rq * 68 + ni * 16 + (lane & 15)] = accO[mi][ni][r];
        if ((lane & 15) == 0) MOw[rq * 68 + 64] = accO[mi][4][r];
      }
    }
  }
  __syncthreads();
  if (w == 0) {
    const float* MOp = (const float*)LB;
#pragma unroll
    for (int mi = 0; mi < 2; ++mi) {
#pragma unroll
      for (int r = 0; r < 4; ++r) {
        int rq = mi * 16 + ((lane >> 4) << 2) + r;
        float m0 = MR[0][rq], m1 = MR[1][rq], m2 = MR[2][rq], m3 = MR[3][rq];
        float M = fmaxf(fmaxf(m0, m1), fmaxf(m2, m3));
        float a0 = exp2f(m0 - M), a1 = exp2f(m1 - M);
        float a2 = exp2f(m2 - M), a3 = exp2f(m3 - M);
        float denom = a0 * accO[mi][4][r] + a1 * MOp[(0 * 32 + rq) * 68 + 64] +
                      a2 * MOp[(1 * 32 + rq) * 68 + 64] + a3 * MOp[(2 * 32 + rq) * 68 + 64];
        float inv = 1.0f / denom;
        int t = q0w + rq;
#pragma unroll
        for (int ni = 0; ni < 4; ++ni) {
          int dh = ni * 16 + (lane & 15);
          float o = a0 * accO[mi][ni][r] + a1 * MOp[(0 * 32 + rq) * 68 + dh] +
                    a2 * MOp[(1 * 32 + rq) * 68 + dh] + a3 * MOp[(2 * 32 + rq) * 68 + dh];
          AO[(size_t)t * DD + h * DK + dh] = f2bf(o * inv);
        }
      }
    }
  }
}

// ---------------- output projection + bias (f32 out) ----------------
__global__ __launch_bounds__(256) void gemm_o(
    const unsigned short* __restrict__ A, const unsigned short* __restrict__ W,
    const float* __restrict__ bias, float* __restrict__ out) {
  __shared__ unsigned short Ash[128 * 64];
  __shared__ unsigned short Bsh[128 * 64];
  const int brow = blockIdx.x * 128;
  const int bcol = blockIdx.y * 128;
  const int tid = threadIdx.x;
  const int lane = tid & 63;
  const int w = tid >> 6;
  const int wr = w >> 1, wc = w & 1;
  const char* Ab = (const char*)A + (size_t)brow * (DD * 2);
  const char* Wb = (const char*)W + (size_t)bcol * (DD * 2);
  char* AshB = (char*)Ash;
  char* BshB = (char*)Bsh;
  f32x4 acc[4][4];
#pragma unroll
  for (int mi = 0; mi < 4; ++mi)
#pragma unroll
    for (int ni = 0; ni < 4; ++ni)
#pragma unroll
      for (int r = 0; r < 4; ++r) acc[mi][ni][r] = 0.0f;

  for (int k0 = 0; k0 < DD; k0 += 64) {
    __syncthreads();
#pragma unroll
    for (int it = 0; it < 4; ++it) {
      int c = it * 256 + tid;
      int row = c >> 3;
      int xb = (c & 7) << 4;
      int sxb = xb ^ ((row & 7) << 4);
      int ldso = (it * 256 + (tid & 192)) << 4;
      gload16(Ab + (size_t)row * (DD * 2) + k0 * 2 + sxb, AshB + ldso);
      gload16(Wb + (size_t)row * (DD * 2) + k0 * 2 + sxb, BshB + ldso);
    }
    __syncthreads();
#pragma unroll
    for (int ks = 0; ks < 2; ++ks) {
      bf16x8 af[4], bfr[4];
      int colb = ks * 64 + ((lane >> 4) << 4);
#pragma unroll
      for (int mi = 0; mi < 4; ++mi) {
        int row = wr * 64 + mi * 16 + (lane & 15);
        af[mi] = *(const bf16x8*)(AshB + row * 128 + (colb ^ ((row & 7) << 4)));
      }
#pragma unroll
      for (int ni = 0; ni < 4; ++ni) {
        int row = wc * 64 + ni * 16 + (lane & 15);
        bfr[ni] = *(const bf16x8*)(BshB + row * 128 + (colb ^ ((row & 7) << 4)));
      }
#pragma unroll
      for (int mi = 0; mi < 4; ++mi)
#pragma unroll
        for (int ni = 0; ni < 4; ++ni)
          acc[mi][ni] = __builtin_amdgcn_mfma_f32_16x16x32_bf16(af[mi], bfr[ni], acc[mi][ni], 0, 0, 0);
    }
  }
#pragma unroll
  for (int mi = 0; mi < 4; ++mi)
#pragma unroll
    for (int r = 0; r < 4; ++r) {
      int t = brow + wr * 64 + mi * 16 + ((lane >> 4) << 2) + r;
#pragma unroll
      for (int ni = 0; ni < 4; ++ni) {
        int o = bcol + wc * 64 + ni * 16 + (lane & 15);
        out[(size_t)t * DD + o] = acc[mi][ni][r] + bias[o];
      }
    }
}

// ---------------- launch ----------------
extern "C" void kernel_launch(void* const* d_in, const int* in_sizes, int n_in,
                              void* d_out, int out_size, void* d_ws, size_t ws_size,
                              hipStream_t stream) {
  const float* q  = (const float*)d_in[0];
  const float* k  = (const float*)d_in[1];
  const float* v  = (const float*)d_in[2];
  const int* pos  = (const int*)d_in[3];
  const float* wq = (const float*)d_in[4];
  const float* wk = (const float*)d_in[5];
  const float* wv = (const float*)d_in[6];
  const float* wo = (const float*)d_in[7];
  const float* wob = (const float*)d_in[8];
  float* out = (float*)d_out;
  char* ws = (char*)d_ws;

  const size_t MB = 1u << 20;
  unsigned short* XQ = (unsigned short*)(ws + 0 * MB);
  unsigned short* XK = (unsigned short*)(ws + 4 * MB);
  unsigned short* XV = (unsigned short*)(ws + 8 * MB);
  unsigned short* WQ = (unsigned short*)(ws + 12 * MB);
  unsigned short* WK = (unsigned short*)(ws + 14 * MB);
  unsigned short* WV = (unsigned short*)(ws + 16 * MB);
  unsigned short* WO = (unsigned short*)(ws + 18 * MB);
  unsigned short* QF = (unsigned short*)(ws + 20 * MB);
  unsigned short* KF = (unsigned short*)(ws + 24 * MB);
  unsigned short* VF = (unsigned short*)(ws + 28 * MB);
  unsigned short* AOb = (unsigned short*)(ws + 32 * MB);
  float* COS = (float*)(ws + 36 * MB);
  float* SIN = (float*)(ws + 36 * MB + 262144);

  hipLaunchKernelGGL(cvt_all, dim3(5120), dim3(256), 0, stream,
                     q, k, v, wq, wk, wv, wo, XQ, XK, XV, WQ, WK, WV, WO);
  hipLaunchKernelGGL(rope_tab, dim3(256), dim3(256), 0, stream, pos, COS, SIN);
  hipLaunchKernelGGL(gemm_qkv, dim3(16, 8, 3), dim3(256), 0, stream,
                     XQ, XK, XV, WQ, WK, WV, QF, KF, VF, COS, SIN);
  hipLaunchKernelGGL(attn_fa, dim3(1024), dim3(256), 0, stream, QF, KF, VF, AOb);
  hipLaunchKernelGGL(gemm_o, dim3(16, 8), dim3(256), 0, stream, AOb, WO, wob, out);
}

// Round 7
// 84.652 us; speedup vs baseline: 1.9643x; 1.1906x over previous
//
#include <hip/hip_runtime.h>
#include <hip/hip_bf16.h>
#include <stdint.h>

#define TT 2048
#define DD 1024
#define NH 16
#define DK 64

typedef __attribute__((ext_vector_type(8))) short bf16x8;
typedef __attribute__((ext_vector_type(4))) float f32x4;
typedef __attribute__((ext_vector_type(8))) unsigned short u16x8;
typedef __attribute__((ext_vector_type(4))) unsigned short u16x4;

__device__ __forceinline__ unsigned short f2bf(float f) {
  union { float f; unsigned u; } x; x.f = f;
  unsigned r = (x.u + 0x7FFFu + ((x.u >> 16) & 1u)) >> 16;
  return (unsigned short)r;
}

__device__ __forceinline__ void gload16(const void* g, void* l) {
  __builtin_amdgcn_global_load_lds(
      (const __attribute__((address_space(1))) unsigned int*)g,
      (__attribute__((address_space(3))) unsigned int*)l, 16, 0, 0);
}

// ---------------- convert f32 -> bf16 ----------------
__global__ __launch_bounds__(256) void cvt_all(
    const float* __restrict__ q, const float* __restrict__ k, const float* __restrict__ v,
    const float* __restrict__ wq, const float* __restrict__ wk, const float* __restrict__ wv,
    const float* __restrict__ wo,
    unsigned short* __restrict__ oq, unsigned short* __restrict__ ok, unsigned short* __restrict__ ov,
    unsigned short* __restrict__ owq, unsigned short* __restrict__ owk, unsigned short* __restrict__ owv,
    unsigned short* __restrict__ owo) {
  int b = blockIdx.x;
  const float* src; unsigned short* dst; int sb;
  if (b < 1024)      { src = q;  dst = oq;  sb = b; }
  else if (b < 2048) { src = k;  dst = ok;  sb = b - 1024; }
  else if (b < 3072) { src = v;  dst = ov;  sb = b - 2048; }
  else if (b < 3584) { src = wq; dst = owq; sb = b - 3072; }
  else if (b < 4096) { src = wk; dst = owk; sb = b - 3584; }
  else if (b < 4608) { src = wv; dst = owv; sb = b - 4096; }
  else               { src = wo; dst = owo; sb = b - 4608; }
  size_t i0 = (size_t)sb * 2048 + (size_t)threadIdx.x * 8;
  f32x4 a = *(const f32x4*)(src + i0);
  f32x4 c = *(const f32x4*)(src + i0 + 4);
  u16x8 r;
#pragma unroll
  for (int j = 0; j < 4; ++j) { r[j] = f2bf(a[j]); r[j + 4] = f2bf(c[j]); }
  *(u16x8*)(dst + i0) = r;
}

// ---------------- RoPE cos/sin table ----------------
__global__ __launch_bounds__(256) void rope_tab(const int* __restrict__ pos,
                                                float* __restrict__ cosT,
                                                float* __restrict__ sinT) {
  int idx = blockIdx.x * 256 + threadIdx.x;  // 2048*32
  int t = idx >> 5, i = idx & 31;
  float inv = exp2f((float)i * -0.41524101186092028f);  // 10000^(-i/32)
  float ang = (float)pos[t] * inv;
  cosT[idx] = cosf(ang);
  sinT[idx] = sinf(ang);
}

// ---------------- fused QKV projection + RoPE ----------------
// Outputs in MFMA FRAGMENT-NATIVE layouts (attn loads = base + lane*16):
//  QF[h][qw][mi][ks][lane], KF[h][kt][ks][ni][lane], VF[h][kt][ks][ni][lane]
__global__ __launch_bounds__(256) void gemm_qkv(
    const unsigned short* __restrict__ xq, const unsigned short* __restrict__ xk,
    const unsigned short* __restrict__ xv,
    const unsigned short* __restrict__ wqb, const unsigned short* __restrict__ wkb,
    const unsigned short* __restrict__ wvb,
    unsigned short* __restrict__ QF, unsigned short* __restrict__ KF,
    unsigned short* __restrict__ VF,
    const float* __restrict__ cosT, const float* __restrict__ sinT) {
  __shared__ unsigned short Ash[128 * 64];
  __shared__ unsigned short Bsh[128 * 64];
  const int z = blockIdx.z;
  const unsigned short* A = (z == 0) ? xq : (z == 1) ? xk : xv;
  const unsigned short* W = (z == 0) ? wqb : (z == 1) ? wkb : wvb;
  const int brow = blockIdx.x * 128;
  const int bcol = blockIdx.y * 128;
  const int tid = threadIdx.x;
  const int lane = tid & 63;
  const int w = tid >> 6;
  const int wr = w >> 1, wc = w & 1;
  const char* Ab = (const char*)A + (size_t)brow * (DD * 2);
  const char* Wb = (const char*)W + (size_t)bcol * (DD * 2);
  char* AshB = (char*)Ash;
  char* BshB = (char*)Bsh;
  f32x4 acc[4][4];
#pragma unroll
  for (int mi = 0; mi < 4; ++mi)
#pragma unroll
    for (int ni = 0; ni < 4; ++ni)
#pragma unroll
      for (int r = 0; r < 4; ++r) acc[mi][ni][r] = 0.0f;

  for (int k0 = 0; k0 < DD; k0 += 64) {
    __syncthreads();
#pragma unroll
    for (int it = 0; it < 4; ++it) {
      int c = it * 256 + tid;
      int row = c >> 3;
      int xb = (c & 7) << 4;
      int sxb = xb ^ ((row & 7) << 4);
      int ldso = (it * 256 + (tid & 192)) << 4;
      gload16(Ab + (size_t)row * (DD * 2) + k0 * 2 + sxb, AshB + ldso);
      gload16(Wb + (size_t)row * (DD * 2) + k0 * 2 + sxb, BshB + ldso);
    }
    __syncthreads();
#pragma unroll
    for (int ks = 0; ks < 2; ++ks) {
      bf16x8 af[4], bfr[4];
      int colb = ks * 64 + ((lane >> 4) << 4);
#pragma unroll
      for (int mi = 0; mi < 4; ++mi) {
        int row = wr * 64 + mi * 16 + (lane & 15);
        af[mi] = *(const bf16x8*)(AshB + row * 128 + (colb ^ ((row & 7) << 4)));
      }
#pragma unroll
      for (int ni = 0; ni < 4; ++ni) {
        int row = wc * 64 + ni * 16 + (lane & 15);
        bfr[ni] = *(const bf16x8*)(BshB + row * 128 + (colb ^ ((row & 7) << 4)));
      }
#pragma unroll
      for (int mi = 0; mi < 4; ++mi)
#pragma unroll
        for (int ni = 0; ni < 4; ++ni)
          acc[mi][ni] = __builtin_amdgcn_mfma_f32_16x16x32_bf16(af[mi], bfr[ni], acc[mi][ni], 0, 0, 0);
    }
  }

  const int hcol = bcol + wc * 64;
  const int h = hcol >> 6;
  if (z == 0) {
    // Q + RoPE + scale(1/8 * log2e) -> QF fragment-native
    const float sc = 0.18033688011112042f;
#pragma unroll
    for (int mi = 0; mi < 4; ++mi) {
#pragma unroll
      for (int r = 0; r < 4; ++r) {
        int t = brow + wr * 64 + mi * 16 + ((lane >> 4) << 2) + r;
        int qw_ = t >> 5, mif = (t >> 4) & 1, r16 = t & 15;
        size_t fb = (((size_t)(h * 64 + qw_) * 2 + mif) * 2) * 1024;  // bytes, ks=0
#pragma unroll
        for (int ni = 0; ni < 2; ++ni) {
          int dl = ni * 16 + (lane & 15);  // d in [0,32)
          float cv = cosT[t * 32 + dl];
          float sv = sinT[t * 32 + dl];
          float x1 = acc[mi][ni][r];
          float x2 = acc[mi][ni + 2][r];
          size_t off = fb + (size_t)(r16 + 16 * (dl >> 3)) * 16 + (dl & 7) * 2;
          *(unsigned short*)((char*)QF + off) = f2bf((x1 * cv - x2 * sv) * sc);
          *(unsigned short*)((char*)QF + off + 1024) = f2bf((x2 * cv + x1 * sv) * sc);
        }
      }
    }
  } else if (z == 1) {
    // K + RoPE -> KF fragment-native
#pragma unroll
    for (int mi = 0; mi < 4; ++mi) {
#pragma unroll
      for (int r = 0; r < 4; ++r) {
        int t = brow + wr * 64 + mi * 16 + ((lane >> 4) << 2) + r;
        int kt = t >> 6, nif = (t >> 4) & 3, r16 = t & 15;
        size_t fb = (((size_t)(h * 32 + kt) * 2) * 4 + nif) * 1024;  // bytes, ks=0
#pragma unroll
        for (int ni = 0; ni < 2; ++ni) {
          int dl = ni * 16 + (lane & 15);
          float cv = cosT[t * 32 + dl];
          float sv = sinT[t * 32 + dl];
          float x1 = acc[mi][ni][r];
          float x2 = acc[mi][ni + 2][r];
          size_t off = fb + (size_t)(r16 + 16 * (dl >> 3)) * 16 + (dl & 7) * 2;
          *(unsigned short*)((char*)KF + off) = f2bf(x1 * cv - x2 * sv);
          *(unsigned short*)((char*)KF + off + 4096) = f2bf(x2 * cv + x1 * sv);  // ks=1
        }
      }
    }
  } else {
    // V -> VF fragment-native
#pragma unroll
    for (int mi = 0; mi < 4; ++mi) {
      int t0 = brow + wr * 64 + mi * 16 + ((lane >> 4) << 2);
      int kt = t0 >> 6, ksf = (t0 & 63) >> 5, slot = (t0 & 31) >> 3, j0 = t0 & 7;
#pragma unroll
      for (int ni = 0; ni < 4; ++ni) {
        int dh = ni * 16 + (lane & 15);
        int lanef = (dh & 15) + 16 * slot;
        int nif = dh >> 4;
        size_t off = ((((size_t)(h * 32 + kt) * 2 + ksf) * 4 + nif) * 64 + lanef) * 16 + j0 * 2;
        u16x4 pk;
#pragma unroll
        for (int r = 0; r < 4; ++r) pk[r] = f2bf(acc[mi][ni][r]);
        *(u16x4*)((char*)VF + off) = pk;
      }
    }
  }
}

// ---------------- causal flash attention ----------------
// grid 1024: job (h, qw). 4 waves split k-tiles mod 4, 4-way LDS combine.
// Swapped QK^T, defer-max, l via ones-MFMA. Fragment-native coalesced loads.
// __launch_bounds__(256,2): VGPR cap 256 -> hold full prefetch live set with
// NO SCRATCH SPILLS (R6's 132-VGPR alloc spilled ~60 regs/tile) while
// guaranteeing 2 waves/SIMD residency.
__global__ __launch_bounds__(256, 2) void attn_fa(
    const unsigned short* __restrict__ QF, const unsigned short* __restrict__ KF,
    const unsigned short* __restrict__ VF, unsigned short* __restrict__ AO) {
  __shared__ char LB[26624];
  __shared__ float MR[4][32];
  const int tid = threadIdx.x;
  const int lane = tid & 63;
  const int w = tid >> 6;
  const int bid = blockIdx.x;
  const int xcd = bid & 7;
  const int idx = bid >> 3;          // 128 jobs per XCD
  const int h = xcd * 2 + (idx & 1); // 2 heads pinned per XCD
  const int qw = 63 - (idx >> 1);    // biggest jobs dispatch first
  const int q0w = qw * 32;
  const int NT = (qw >> 1) + 1;
  char* PshB = LB + w * 4096;
  const char* Kb = (const char*)KF + (size_t)h * 32 * 8192;  // 8KB per k-tile
  const char* Vb = (const char*)VF + (size_t)h * 32 * 8192;

  // Q fragments: coalesced
  bf16x8 qf[2][2];
  {
    const char* Qb = (const char*)QF + (size_t)(h * 64 + qw) * 4096;
#pragma unroll
    for (int mi = 0; mi < 2; ++mi)
#pragma unroll
      for (int ks = 0; ks < 2; ++ks)
        qf[mi][ks] = *(const bf16x8*)(Qb + (mi * 2 + ks) * 1024 + lane * 16);
  }

  bf16x8 vone;
#pragma unroll
  for (int j = 0; j < 8; ++j) vone[j] = (short)0x3F80;  // bf16 1.0

  f32x4 accO[2][5];  // [..][4] = row-sum l (ones-column MFMA)
  float mrow[2];
#pragma unroll
  for (int mi = 0; mi < 2; ++mi) {
    mrow[mi] = -1e30f;
#pragma unroll
    for (int ni = 0; ni < 5; ++ni)
#pragma unroll
      for (int r = 0; r < 4; ++r) accO[mi][ni][r] = 0.0f;
  }

  bf16x8 kfA[2][4], kfB[2][4], vf[2][4];
  {
    int kt0 = (w < NT) ? w : 0;
    const char* p = Kb + (size_t)kt0 * 8192 + lane * 16;
#pragma unroll
    for (int ks = 0; ks < 2; ++ks)
#pragma unroll
      for (int ni = 0; ni < 4; ++ni)
        kfA[ks][ni] = *(const bf16x8*)(p + (ks * 4 + ni) * 1024);
  }

  for (int kt = w; kt < NT; kt += 4) {
    {  // V tile: coalesced; issue early, QK+softmax hides latency
      const char* p = Vb + (size_t)kt * 8192 + lane * 16;
#pragma unroll
      for (int ks = 0; ks < 2; ++ks)
#pragma unroll
        for (int ni = 0; ni < 4; ++ni)
          vf[ks][ni] = *(const bf16x8*)(p + (ks * 4 + ni) * 1024);
    }
    f32x4 s[2][4];
#pragma unroll
    for (int mi = 0; mi < 2; ++mi)
#pragma unroll
      for (int ni = 0; ni < 4; ++ni)
#pragma unroll
        for (int r = 0; r < 4; ++r) s[mi][ni][r] = 0.0f;
    // swapped: S^T[k][q] = K-frag (A) x Q-frag (B); D col=q(lane&15), row=k
    __builtin_amdgcn_s_setprio(1);
#pragma unroll
    for (int ks = 0; ks < 2; ++ks)
#pragma unroll
      for (int mi = 0; mi < 2; ++mi)
#pragma unroll
        for (int ni = 0; ni < 4; ++ni)
          s[mi][ni] = __builtin_amdgcn_mfma_f32_16x16x32_bf16(kfA[ks][ni], qf[mi][ks], s[mi][ni], 0, 0, 0);
    __builtin_amdgcn_s_setprio(0);
    if (kt + 4 < NT) {  // prefetch own next K tile
      const char* p = Kb + (size_t)(kt + 4) * 8192 + lane * 16;
#pragma unroll
      for (int ks = 0; ks < 2; ++ks)
#pragma unroll
        for (int ni = 0; ni < 4; ++ni)
          kfB[ks][ni] = *(const bf16x8*)(p + (ks * 4 + ni) * 1024);
    }

    if (kt == NT - 1) {  // diagonal tile: causal mask
#pragma unroll
      for (int mi = 0; mi < 2; ++mi) {
        int qq = q0w + mi * 16 + (lane & 15);
#pragma unroll
        for (int ni = 0; ni < 4; ++ni) {
          int kb = kt * 64 + ni * 16 + ((lane >> 4) << 2);
#pragma unroll
          for (int r = 0; r < 4; ++r)
            if (kb + r > qq) s[mi][ni][r] = -1e30f;
        }
      }
    }
    // row max: 15 in-lane fmax + 2 shuffles (S^T: q = lane&15)
    float rmx[2];
#pragma unroll
    for (int mi = 0; mi < 2; ++mi) {
      f32x4 t;
#pragma unroll
      for (int r = 0; r < 4; ++r)
        t[r] = fmaxf(fmaxf(s[mi][0][r], s[mi][1][r]), fmaxf(s[mi][2][r], s[mi][3][r]));
      float mx = fmaxf(fmaxf(t[0], t[1]), fmaxf(t[2], t[3]));
      mx = fmaxf(mx, __shfl_xor(mx, 16, 64));
      mx = fmaxf(mx, __shfl_xor(mx, 32, 64));
      rmx[mi] = mx;
    }
    // defer-max: rescale only when max grew past threshold (log2 domain)
    bool need = (rmx[0] > mrow[0] + 8.0f) || (rmx[1] > mrow[1] + 8.0f);
    if (__any(need)) {
#pragma unroll
      for (int mi = 0; mi < 2; ++mi) {
        float mn = fmaxf(mrow[mi], rmx[mi]);
        float al = exp2f(mrow[mi] - mn);
        mrow[mi] = mn;
        float ar[4];
#pragma unroll
        for (int r = 0; r < 4; ++r) ar[r] = __shfl(al, ((lane >> 4) << 2) + r, 64);
#pragma unroll
        for (int ni = 0; ni < 5; ++ni)
#pragma unroll
          for (int r = 0; r < 4; ++r) accO[mi][ni][r] *= ar[r];
      }
    }
    // P = exp2(s - m), bf16-pack pairs (consecutive k), b64 store
#pragma unroll
    for (int mi = 0; mi < 2; ++mi) {
      int row = mi * 16 + (lane & 15);
      int rbase = row * 128;
      int sw = (row & 7) << 4;
#pragma unroll
      for (int ni = 0; ni < 4; ++ni) {
        unsigned u0 = __float_as_uint(exp2f(s[mi][ni][0] - mrow[mi]));
        unsigned u1 = __float_as_uint(exp2f(s[mi][ni][1] - mrow[mi]));
        unsigned u2 = __float_as_uint(exp2f(s[mi][ni][2] - mrow[mi]));
        unsigned u3 = __float_as_uint(exp2f(s[mi][ni][3] - mrow[mi]));
        uint2 pk;
        pk.x = (u0 >> 16) | (u1 & 0xFFFF0000u);
        pk.y = (u2 >> 16) | (u3 & 0xFFFF0000u);
        int cb = ni * 32 + ((lane >> 4) << 3);
        *(uint2*)(PshB + rbase + (cb ^ sw)) = pk;
      }
    }
    asm volatile("" ::: "memory");  // order P writes before P reads (wave-local)
    // PV: O += P(A) x V(B); l += P x ones
    __builtin_amdgcn_s_setprio(1);
#pragma unroll
    for (int ks = 0; ks < 2; ++ks) {
      bf16x8 pf[2];
#pragma unroll
      for (int mi = 0; mi < 2; ++mi) {
        int row = mi * 16 + (lane & 15);
        int cb = ks * 64 + ((lane >> 4) << 4);
        pf[mi] = *(const bf16x8*)(PshB + row * 128 + (cb ^ ((row & 7) << 4)));
      }
#pragma unroll
      for (int mi = 0; mi < 2; ++mi) {
#pragma unroll
        for (int ni = 0; ni < 4; ++ni)
          accO[mi][ni] = __builtin_amdgcn_mfma_f32_16x16x32_bf16(pf[mi], vf[ks][ni], accO[mi][ni], 0, 0, 0);
        accO[mi][4] = __builtin_amdgcn_mfma_f32_16x16x32_bf16(pf[mi], vone, accO[mi][4], 0, 0, 0);
      }
    }
    __builtin_amdgcn_s_setprio(0);
#pragma unroll
    for (int ks = 0; ks < 2; ++ks)
#pragma unroll
      for (int ni = 0; ni < 4; ++ni) kfA[ks][ni] = kfB[ks][ni];
  }

  __syncthreads();  // all waves done with P buffers; LB becomes MO partials
  if ((lane >> 4) == 0) {
    MR[w][lane] = mrow[0];
    MR[w][16 + lane] = mrow[1];
  }
  if (w > 0) {
    float* MOw = (float*)LB + (size_t)(w - 1) * 32 * 68;
#pragma unroll
    for (int mi = 0; mi < 2; ++mi) {
#pragma unroll
      for (int r = 0; r < 4; ++r) {
        int rq = mi * 16 + ((lane >> 4) << 2) + r;
#pragma unroll
        for (int ni = 0; ni < 4; ++ni)
          MOw[rq * 68 + ni * 16 + (lane & 15)] = accO[mi][ni][r];
        if ((lane & 15) == 0) MOw[rq * 68 + 64] = accO[mi][4][r];
      }
    }
  }
  __syncthreads();
  if (w == 0) {
    const float* MOp = (const float*)LB;
#pragma unroll
    for (int mi = 0; mi < 2; ++mi) {
#pragma unroll
      for (int r = 0; r < 4; ++r) {
        int rq = mi * 16 + ((lane >> 4) << 2) + r;
        float m0 = MR[0][rq], m1 = MR[1][rq], m2 = MR[2][rq], m3 = MR[3][rq];
        float M = fmaxf(fmaxf(m0, m1), fmaxf(m2, m3));
        float a0 = exp2f(m0 - M), a1 = exp2f(m1 - M);
        float a2 = exp2f(m2 - M), a3 = exp2f(m3 - M);
        float denom = a0 * accO[mi][4][r] + a1 * MOp[(0 * 32 + rq) * 68 + 64] +
                      a2 * MOp[(1 * 32 + rq) * 68 + 64] + a3 * MOp[(2 * 32 + rq) * 68 + 64];
        float inv = 1.0f / denom;
        int t = q0w + rq;
#pragma unroll
        for (int ni = 0; ni < 4; ++ni) {
          int dh = ni * 16 + (lane & 15);
          float o = a0 * accO[mi][ni][r] + a1 * MOp[(0 * 32 + rq) * 68 + dh] +
                    a2 * MOp[(1 * 32 + rq) * 68 + dh] + a3 * MOp[(2 * 32 + rq) * 68 + dh];
          AO[(size_t)t * DD + h * DK + dh] = f2bf(o * inv);
        }
      }
    }
  }
}

// ---------------- output projection + bias (f32 out) ----------------
__global__ __launch_bounds__(256) void gemm_o(
    const unsigned short* __restrict__ A, const unsigned short* __restrict__ W,
    const float* __restrict__ bias, float* __restrict__ out) {
  __shared__ unsigned short Ash[128 * 64];
  __shared__ unsigned short Bsh[128 * 64];
  const int brow = blockIdx.x * 128;
  const int bcol = blockIdx.y * 128;
  const int tid = threadIdx.x;
  const int lane = tid & 63;
  const int w = tid >> 6;
  const int wr = w >> 1, wc = w & 1;
  const char* Ab = (const char*)A + (size_t)brow * (DD * 2);
  const char* Wb = (const char*)W + (size_t)bcol * (DD * 2);
  char* AshB = (char*)Ash;
  char* BshB = (char*)Bsh;
  f32x4 acc[4][4];
#pragma unroll
  for (int mi = 0; mi < 4; ++mi)
#pragma unroll
    for (int ni = 0; ni < 4; ++ni)
#pragma unroll
      for (int r = 0; r < 4; ++r) acc[mi][ni][r] = 0.0f;

  for (int k0 = 0; k0 < DD; k0 += 64) {
    __syncthreads();
#pragma unroll
    for (int it = 0; it < 4; ++it) {
      int c = it * 256 + tid;
      int row = c >> 3;
      int xb = (c & 7) << 4;
      int sxb = xb ^ ((row & 7) << 4);
      int ldso = (it * 256 + (tid & 192)) << 4;
      gload16(Ab + (size_t)row * (DD * 2) + k0 * 2 + sxb, AshB + ldso);
      gload16(Wb + (size_t)row * (DD * 2) + k0 * 2 + sxb, BshB + ldso);
    }
    __syncthreads();
#pragma unroll
    for (int ks = 0; ks < 2; ++ks) {
      bf16x8 af[4], bfr[4];
      int colb = ks * 64 + ((lane >> 4) << 4);
#pragma unroll
      for (int mi = 0; mi < 4; ++mi) {
        int row = wr * 64 + mi * 16 + (lane & 15);
        af[mi] = *(const bf16x8*)(AshB + row * 128 + (colb ^ ((row & 7) << 4)));
      }
#pragma unroll
      for (int ni = 0; ni < 4; ++ni) {
        int row = wc * 64 + ni * 16 + (lane & 15);
        bfr[ni] = *(const bf16x8*)(BshB + row * 128 + (colb ^ ((row & 7) << 4)));
      }
#pragma unroll
      for (int mi = 0; mi < 4; ++mi)
#pragma unroll
        for (int ni = 0; ni < 4; ++ni)
          acc[mi][ni] = __builtin_amdgcn_mfma_f32_16x16x32_bf16(af[mi], bfr[ni], acc[mi][ni], 0, 0, 0);
    }
  }
#pragma unroll
  for (int mi = 0; mi < 4; ++mi)
#pragma unroll
    for (int r = 0; r < 4; ++r) {
      int t = brow + wr * 64 + mi * 16 + ((lane >> 4) << 2) + r;
#pragma unroll
      for (int ni = 0; ni < 4; ++ni) {
        int o = bcol + wc * 64 + ni * 16 + (lane & 15);
        out[(size_t)t * DD + o] = acc[mi][ni][r] + bias[o];
      }
    }
}

// ---------------- launch ----------------
extern "C" void kernel_launch(void* const* d_in, const int* in_sizes, int n_in,
                              void* d_out, int out_size, void* d_ws, size_t ws_size,
                              hipStream_t stream) {
  const float* q  = (const float*)d_in[0];
  const float* k  = (const float*)d_in[1];
  const float* v  = (const float*)d_in[2];
  const int* pos  = (const int*)d_in[3];
  const float* wq = (const float*)d_in[4];
  const float* wk = (const float*)d_in[5];
  const float* wv = (const float*)d_in[6];
  const float* wo = (const float*)d_in[7];
  const float* wob = (const float*)d_in[8];
  float* out = (float*)d_out;
  char* ws = (char*)d_ws;

  const size_t MB = 1u << 20;
  unsigned short* XQ = (unsigned short*)(ws + 0 * MB);
  unsigned short* XK = (unsigned short*)(ws + 4 * MB);
  unsigned short* XV = (unsigned short*)(ws + 8 * MB);
  unsigned short* WQ = (unsigned short*)(ws + 12 * MB);
  unsigned short* WK = (unsigned short*)(ws + 14 * MB);
  unsigned short* WV = (unsigned short*)(ws + 16 * MB);
  unsigned short* WO = (unsigned short*)(ws + 18 * MB);
  unsigned short* QF = (unsigned short*)(ws + 20 * MB);
  unsigned short* KF = (unsigned short*)(ws + 24 * MB);
  unsigned short* VF = (unsigned short*)(ws + 28 * MB);
  unsigned short* AOb = (unsigned short*)(ws + 32 * MB);
  float* COS = (float*)(ws + 36 * MB);
  float* SIN = (float*)(ws + 36 * MB + 262144);

  hipLaunchKernelGGL(cvt_all, dim3(5120), dim3(256), 0, stream,
                     q, k, v, wq, wk, wv, wo, XQ, XK, XV, WQ, WK, WV, WO);
  hipLaunchKernelGGL(rope_tab, dim3(256), dim3(256), 0, stream, pos, COS, SIN);
  hipLaunchKernelGGL(gemm_qkv, dim3(16, 8, 3), dim3(256), 0, stream,
                     XQ, XK, XV, WQ, WK, WV, QF, KF, VF, COS, SIN);
  hipLaunchKernelGGL(attn_fa, dim3(1024), dim3(256), 0, stream, QF, KF, VF, AOb);
  hipLaunchKernelGGL(gemm_o, dim3(16, 8), dim3(256), 0, stream, AOb, WO, wob, out);
}